// Round 1
// baseline (846.411 us; speedup 1.0000x reference)
//
#include <hip/hip_runtime.h>
#include <cstdint>
#include <cstddef>

#define B_ 8
#define N_ 4096
#define C_ 512
#define KV_ 960
#define DQ 128
#define DK 240
#define NSPLIT 16
#define NCHUNK (N_ / NSPLIT)  // 256

// ---------------------------------------------------------------------------
// K1: S[b,h,i,j] = sum_n emb1[b,n,h*128+i] * emb_all[b,n,h*240+j]
// Split-K over n into NSPLIT partials (deterministic, no atomics).
// grid (32 bh, NSPLIT), block 256. Thread tile 8i x 15j in registers.
// ---------------------------------------------------------------------------
__global__ __launch_bounds__(256) void k1_spartial(const float* __restrict__ emb1,
                                                   const float* __restrict__ emba,
                                                   float* __restrict__ P) {
  const int bh = blockIdx.x;
  const int split = blockIdx.y;
  const int b = bh >> 2, h = bh & 3;
  const int n0 = split * NCHUNK;
  __shared__ float sa[8][DQ];
  __shared__ float sb[8][DK];
  const int t = threadIdx.x;
  const int ti = t >> 4, tj = t & 15;
  const int i0 = ti * 8, j0 = tj * 15;
  float acc[8][15];
#pragma unroll
  for (int x = 0; x < 8; ++x)
#pragma unroll
    for (int y = 0; y < 15; ++y) acc[x][y] = 0.f;

  const float* e1 = emb1 + (size_t)b * N_ * C_ + h * DQ;
  const float* ea = emba + (size_t)b * N_ * KV_ + h * DK;

  for (int nn = 0; nn < NCHUNK; nn += 8) {
    __syncthreads();
#pragma unroll
    for (int q = 0; q < 4; ++q) {  // 8*128 = 1024 elems
      int idx = t + q * 256;
      int r = idx >> 7, c = idx & 127;
      sa[r][c] = e1[(size_t)(n0 + nn + r) * C_ + c];
    }
#pragma unroll
    for (int q = 0; q < 8; ++q) {  // 8*240 = 1920 elems
      int idx = t + q * 256;
      if (idx < 8 * DK) {
        int r = idx / DK, c = idx - r * DK;
        sb[r][c] = ea[(size_t)(n0 + nn + r) * KV_ + c];
      }
    }
    __syncthreads();
#pragma unroll
    for (int r = 0; r < 8; ++r) {
      float av[8], bv[15];
#pragma unroll
      for (int x = 0; x < 8; ++x) av[x] = sa[r][i0 + x];
#pragma unroll
      for (int y = 0; y < 15; ++y) bv[y] = sb[r][j0 + y];
#pragma unroll
      for (int x = 0; x < 8; ++x)
#pragma unroll
        for (int y = 0; y < 15; ++y) acc[x][y] = fmaf(av[x], bv[y], acc[x][y]);
    }
  }
  float* p = P + ((size_t)split * 32 + bh) * (DQ * DK);
#pragma unroll
  for (int x = 0; x < 8; ++x)
#pragma unroll
    for (int y = 0; y < 15; ++y) p[(i0 + x) * DK + j0 + y] = acc[x][y];
}

// ---------------------------------------------------------------------------
// K1b: reduce NSPLIT partials -> S. float4-vectorized. grid 960, block 256.
// ---------------------------------------------------------------------------
__global__ __launch_bounds__(256) void k_reduce(const float4* __restrict__ P,
                                                float4* __restrict__ S) {
  const int i = blockIdx.x * 256 + threadIdx.x;  // < 245760
  float4 a = P[i];
#pragma unroll
  for (int s = 1; s < NSPLIT; ++s) {
    float4 v = P[(size_t)s * 245760 + i];
    a.x += v.x; a.y += v.y; a.z += v.z; a.w += v.w;
  }
  S[i] = a;
}

// ---------------------------------------------------------------------------
// Generic small GEMM over the 32 (b,h) problems:
//   C[m,n] = scale * sum_k A[m*sa0 + k*sa1] * B[k*sb0 + n*sb1]
// N is fixed at 240. grid (32, M/64), block 256, thread tile 4m x 15n.
// ---------------------------------------------------------------------------
__global__ __launch_bounds__(256) void k_small_gemm(
    const float* __restrict__ A, int a_h, int a_b, int sa0, int sa1,
    const float* __restrict__ B, int b_h, int b_b, int sb0, int sb1,
    float* __restrict__ C, int c_h, int c_b, int ldc, int K, float scale) {
  const int bh = blockIdx.x;
  const int b = bh >> 2, h = bh & 3;
  const int m0 = blockIdx.y * 64;
  const float* Ab = A + (size_t)h * a_h + (size_t)b * a_b;
  const float* Bb = B + (size_t)h * b_h + (size_t)b * b_b;
  float* Cb = C + (size_t)h * c_h + (size_t)b * c_b;

  __shared__ float Ast[16][64];
  __shared__ float Bst[16][DK];
  const int t = threadIdx.x;
  const int tm = t >> 4, tn = t & 15;
  const int mi = tm * 4, nj = tn * 15;
  float acc[4][15];
#pragma unroll
  for (int x = 0; x < 4; ++x)
#pragma unroll
    for (int y = 0; y < 15; ++y) acc[x][y] = 0.f;

  for (int k0 = 0; k0 < K; k0 += 16) {
    __syncthreads();
#pragma unroll
    for (int q = 0; q < 4; ++q) {  // A chunk 64x16
      int idx = t + q * 256;
      int m = idx >> 4, k = idx & 15;
      Ast[k][m] = Ab[(size_t)(m0 + m) * sa0 + (size_t)(k0 + k) * sa1];
    }
#pragma unroll
    for (int q = 0; q < 15; ++q) {  // B chunk 16x240
      int idx = t + q * 256;
      int k = idx / DK, n = idx - k * DK;
      Bst[k][n] = Bb[(size_t)(k0 + k) * sb0 + (size_t)n * sb1];
    }
    __syncthreads();
#pragma unroll
    for (int kk = 0; kk < 16; ++kk) {
      float a4[4], bn[15];
#pragma unroll
      for (int x = 0; x < 4; ++x) a4[x] = Ast[kk][mi + x];
#pragma unroll
      for (int y = 0; y < 15; ++y) bn[y] = Bst[kk][nj + y];
#pragma unroll
      for (int x = 0; x < 4; ++x)
#pragma unroll
        for (int y = 0; y < 15; ++y) acc[x][y] = fmaf(a4[x], bn[y], acc[x][y]);
    }
  }
#pragma unroll
  for (int x = 0; x < 4; ++x)
#pragma unroll
    for (int y = 0; y < 15; ++y)
      Cb[(size_t)(m0 + mi + x) * ldc + nj + y] = acc[x][y] * scale;
}

// ---------------------------------------------------------------------------
// InstanceNorm (over 128x240 map, biased var, eps 1e-5) + softmax over dk.
// grid 32, block 256 (threads 0..127 each own one row for the softmax part).
// ---------------------------------------------------------------------------
__global__ __launch_bounds__(256) void k_inorm_softmax(const float* __restrict__ SC,
                                                       float* __restrict__ PR) {
  const int bh = blockIdx.x;
  const float* s = SC + (size_t)bh * DQ * DK;
  float* p = PR + (size_t)bh * DQ * DK;
  const int t = threadIdx.x;
  float sum = 0.f, sq = 0.f;
  for (int i = t; i < DQ * DK; i += 256) {
    float v = s[i];
    sum += v;
    sq = fmaf(v, v, sq);
  }
#pragma unroll
  for (int o = 32; o > 0; o >>= 1) {
    sum += __shfl_down(sum, o);
    sq += __shfl_down(sq, o);
  }
  __shared__ float s1[4], s2[4];
  if ((t & 63) == 0) { s1[t >> 6] = sum; s2[t >> 6] = sq; }
  __syncthreads();
  const float ts = s1[0] + s1[1] + s1[2] + s1[3];
  const float tq = s2[0] + s2[1] + s2[2] + s2[3];
  const float mu = ts * (1.f / (DQ * DK));
  const float var = tq * (1.f / (DQ * DK)) - mu * mu;
  const float rstd = rsqrtf(var + 1e-5f);
  if (t < DQ) {
    const float* row = s + t * DK;
    float* prow = p + t * DK;
    float m = -1e30f;
    for (int k = 0; k < DK; ++k) m = fmaxf(m, (row[k] - mu) * rstd);
    float acc = 0.f;
    for (int k = 0; k < DK; ++k) {
      float e = __expf((row[k] - mu) * rstd - m);
      prow[k] = e;
      acc += e;
    }
    const float inv = 1.f / acc;
    for (int k = 0; k < DK; ++k) prow[k] *= inv;
  }
}

// ---------------------------------------------------------------------------
// K3: O1[b,n,e] = sum_g emb_all[b,n,g] * W3cat[b,e,g]
// Per b: [4096x960] @ [512x960]^T. grid (8, 32, 4), block 256.
// Block tile 128x128, K-chunk 16, thread tile 8x8.
// ---------------------------------------------------------------------------
__global__ __launch_bounds__(256) void k3_gemm(const float* __restrict__ A,
                                               const float* __restrict__ Bw,
                                               float* __restrict__ C) {
  const int b = blockIdx.x, mt = blockIdx.y, nt = blockIdx.z;
  const float* Ab = A + (size_t)b * N_ * KV_ + (size_t)mt * 128 * KV_;
  const float* Bb = Bw + (size_t)b * C_ * KV_ + (size_t)nt * 128 * KV_;
  float* Cb = C + (size_t)b * N_ * C_ + (size_t)mt * 128 * C_ + nt * 128;

  __shared__ float Ast[16][128];
  __shared__ float Bst[16][128];
  const int t = threadIdx.x;
  const int tr = t >> 1;
  const int tsg = (t & 1) * 8;
  const int i0 = (t >> 4) * 8, j0 = (t & 15) * 8;
  float acc[8][8];
#pragma unroll
  for (int x = 0; x < 8; ++x)
#pragma unroll
    for (int y = 0; y < 8; ++y) acc[x][y] = 0.f;

  for (int k0 = 0; k0 < KV_; k0 += 16) {
    __syncthreads();
    const float4* ap = (const float4*)(Ab + (size_t)tr * KV_ + k0 + tsg);
    float4 a0 = ap[0], a1 = ap[1];
    const float4* bp = (const float4*)(Bb + (size_t)tr * KV_ + k0 + tsg);
    float4 b0 = bp[0], b1 = bp[1];
    Ast[tsg + 0][tr] = a0.x; Ast[tsg + 1][tr] = a0.y;
    Ast[tsg + 2][tr] = a0.z; Ast[tsg + 3][tr] = a0.w;
    Ast[tsg + 4][tr] = a1.x; Ast[tsg + 5][tr] = a1.y;
    Ast[tsg + 6][tr] = a1.z; Ast[tsg + 7][tr] = a1.w;
    Bst[tsg + 0][tr] = b0.x; Bst[tsg + 1][tr] = b0.y;
    Bst[tsg + 2][tr] = b0.z; Bst[tsg + 3][tr] = b0.w;
    Bst[tsg + 4][tr] = b1.x; Bst[tsg + 5][tr] = b1.y;
    Bst[tsg + 6][tr] = b1.z; Bst[tsg + 7][tr] = b1.w;
    __syncthreads();
#pragma unroll
    for (int kk = 0; kk < 16; ++kk) {
      float4 av0 = *(const float4*)&Ast[kk][i0];
      float4 av1 = *(const float4*)&Ast[kk][i0 + 4];
      float4 bv0 = *(const float4*)&Bst[kk][j0];
      float4 bv1 = *(const float4*)&Bst[kk][j0 + 4];
      float av[8] = {av0.x, av0.y, av0.z, av0.w, av1.x, av1.y, av1.z, av1.w};
      float bv[8] = {bv0.x, bv0.y, bv0.z, bv0.w, bv1.x, bv1.y, bv1.z, bv1.w};
#pragma unroll
      for (int x = 0; x < 8; ++x)
#pragma unroll
        for (int y = 0; y < 8; ++y) acc[x][y] = fmaf(av[x], bv[y], acc[x][y]);
    }
  }
#pragma unroll
  for (int x = 0; x < 8; ++x) {
    float4 v0 = make_float4(acc[x][0], acc[x][1], acc[x][2], acc[x][3]);
    float4 v1 = make_float4(acc[x][4], acc[x][5], acc[x][6], acc[x][7]);
    *(float4*)(Cb + (size_t)(i0 + x) * C_ + j0) = v0;
    *(float4*)(Cb + (size_t)(i0 + x) * C_ + j0 + 4) = v1;
  }
}

// ---------------------------------------------------------------------------
// Workspace layout (bytes):
//   P (split-K partials) : [0, 62914560)          -- freed after k_reduce
//   W2 (reuses P region) : [0, 15728640)
//   W3cat                : [16777216, 32505856)
//   S                    : [62914560, 66846720)
//   U                    : [66846720, 70778880)
//   scores               : [70778880, 74711040)
//   probs                : [74711040, 78643200)
// Total ~78.6 MB. Every byte read is written earlier in the same call.
// ---------------------------------------------------------------------------
extern "C" void kernel_launch(void* const* d_in, const int* in_sizes, int n_in,
                              void* d_out, int out_size, void* d_ws, size_t ws_size,
                              hipStream_t stream) {
  const float* emb1 = (const float*)d_in[0];
  const float* emba = (const float*)d_in[1];
  const float* Wq   = (const float*)d_in[2];
  const float* Wk   = (const float*)d_in[3];
  const float* Wv   = (const float*)d_in[4];
  const float* Wo   = (const float*)d_in[5];
  float* out = (float*)d_out;
  char* ws = (char*)d_ws;

  float* P   = (float*)(ws);
  float* W2  = (float*)(ws);
  float* W3  = (float*)(ws + 16777216);
  float* S   = (float*)(ws + 62914560);
  float* U   = (float*)(ws + 66846720);
  float* SCb = (float*)(ws + 70778880);
  float* PRb = (float*)(ws + 74711040);

  // 1) S partials + reduce
  k1_spartial<<<dim3(32, NSPLIT), 256, 0, stream>>>(emb1, emba, P);
  k_reduce<<<960, 256, 0, stream>>>((const float4*)P, (float4*)S);

  // 2) U = Wq[h] @ S[b,h]           (M=128, K=128)
  k_small_gemm<<<dim3(32, 2), 256, 0, stream>>>(
      Wq, 16384, 0, 128, 1,
      S, 30720, 122880, 240, 1,
      U, 30720, 122880, 240, 128, 1.0f);

  // 3) scores = (U @ Wk^T) / sqrt(960)   (M=128, K=240)
  k_small_gemm<<<dim3(32, 2), 256, 0, stream>>>(
      U, 30720, 122880, 240, 1,
      Wk, 0, 0, 1, 240,
      SCb, 30720, 122880, 240, 240, 0.0322748612183951f);

  // 4) InstanceNorm + softmax -> probs
  k_inorm_softmax<<<32, 256, 0, stream>>>(SCb, PRb);

  // 5) W2[e,k] = sum_c Wo[e,4c+h] * probs[c,k]   (M=512, K=128)
  k_small_gemm<<<dim3(32, 8), 256, 0, stream>>>(
      Wo, 1, 0, 512, 4,
      PRb, 30720, 122880, 240, 1,
      W2, 122880, 491520, 240, 128, 1.0f);

  // 6) W3cat[b,e,h*240+d] = sum_k W2[e,k] * Wv[k,d]  (M=512, K=240)
  k_small_gemm<<<dim3(32, 8), 256, 0, stream>>>(
      W2, 122880, 491520, 240, 1,
      Wv, 0, 0, 240, 1,
      W3, 240, 491520, 960, 240, 1.0f);

  // 7) O1[b] = emb_all[b] @ W3cat[b]^T
  k3_gemm<<<dim3(8, 32, 4), 256, 0, stream>>>(emba, W3, out);
}

// Round 2
// 559.596 us; speedup vs baseline: 1.5125x; 1.5125x over previous
//
#include <hip/hip_runtime.h>
#include <cstdint>
#include <cstddef>

#define B_ 8
#define N_ 4096
#define C_ 512
#define KV_ 960
#define DQ 128
#define DK 240
#define NSPLIT 16
#define NCHUNK (N_ / NSPLIT)  // 256

typedef __attribute__((ext_vector_type(8))) short bf16x8;
typedef __attribute__((ext_vector_type(4))) float f32x4;
#define AS1 __attribute__((address_space(1)))
#define AS3 __attribute__((address_space(3)))

__device__ __forceinline__ ushort f2bf(float f) {
  uint32_t u = __float_as_uint(f);
  u += 0x7FFFu + ((u >> 16) & 1u);  // RNE
  return (ushort)(u >> 16);
}

// ---------------------------------------------------------------------------
// K1: S[b,h,i,j] = sum_n emb1[b,n,h*128+i] * emb_all[b,n,h*240+j]
// Split-K over n into NSPLIT partials (deterministic). f32 (unchanged this rd)
// ---------------------------------------------------------------------------
__global__ __launch_bounds__(256) void k1_spartial(const float* __restrict__ emb1,
                                                   const float* __restrict__ emba,
                                                   float* __restrict__ P) {
  const int bh = blockIdx.x;
  const int split = blockIdx.y;
  const int b = bh >> 2, h = bh & 3;
  const int n0 = split * NCHUNK;
  __shared__ float sa[8][DQ];
  __shared__ float sb[8][DK];
  const int t = threadIdx.x;
  const int ti = t >> 4, tj = t & 15;
  const int i0 = ti * 8, j0 = tj * 15;
  float acc[8][15];
#pragma unroll
  for (int x = 0; x < 8; ++x)
#pragma unroll
    for (int y = 0; y < 15; ++y) acc[x][y] = 0.f;

  const float* e1 = emb1 + (size_t)b * N_ * C_ + h * DQ;
  const float* ea = emba + (size_t)b * N_ * KV_ + h * DK;

  for (int nn = 0; nn < NCHUNK; nn += 8) {
    __syncthreads();
#pragma unroll
    for (int q = 0; q < 4; ++q) {
      int idx = t + q * 256;
      int r = idx >> 7, c = idx & 127;
      sa[r][c] = e1[(size_t)(n0 + nn + r) * C_ + c];
    }
#pragma unroll
    for (int q = 0; q < 8; ++q) {
      int idx = t + q * 256;
      if (idx < 8 * DK) {
        int r = idx / DK, c = idx - r * DK;
        sb[r][c] = ea[(size_t)(n0 + nn + r) * KV_ + c];
      }
    }
    __syncthreads();
#pragma unroll
    for (int r = 0; r < 8; ++r) {
      float av[8], bv[15];
#pragma unroll
      for (int x = 0; x < 8; ++x) av[x] = sa[r][i0 + x];
#pragma unroll
      for (int y = 0; y < 15; ++y) bv[y] = sb[r][j0 + y];
#pragma unroll
      for (int x = 0; x < 8; ++x)
#pragma unroll
        for (int y = 0; y < 15; ++y) acc[x][y] = fmaf(av[x], bv[y], acc[x][y]);
    }
  }
  float* p = P + ((size_t)split * 32 + bh) * (DQ * DK);
#pragma unroll
  for (int x = 0; x < 8; ++x)
#pragma unroll
    for (int y = 0; y < 15; ++y) p[(i0 + x) * DK + j0 + y] = acc[x][y];
}

__global__ __launch_bounds__(256) void k_reduce(const float4* __restrict__ P,
                                                float4* __restrict__ S) {
  const int i = blockIdx.x * 256 + threadIdx.x;
  float4 a = P[i];
#pragma unroll
  for (int s = 1; s < NSPLIT; ++s) {
    float4 v = P[(size_t)s * 245760 + i];
    a.x += v.x; a.y += v.y; a.z += v.z; a.w += v.w;
  }
  S[i] = a;
}

// ---------------------------------------------------------------------------
// f32 -> bf16 (RNE), 4 elems/thread
// ---------------------------------------------------------------------------
__global__ __launch_bounds__(256) void k_cvt(const float4* __restrict__ in,
                                             ushort4* __restrict__ out, int n4) {
  int i = blockIdx.x * 256 + threadIdx.x;
  if (i >= n4) return;
  float4 v = in[i];
  ushort4 o;
  o.x = f2bf(v.x); o.y = f2bf(v.y); o.z = f2bf(v.z); o.w = f2bf(v.w);
  out[i] = o;
}

// ---------------------------------------------------------------------------
// Generic small GEMM over the 32 (b,h) problems, N fixed 240.
// Optional bf16 output (for W3).
// ---------------------------------------------------------------------------
template <bool BF16OUT>
__global__ __launch_bounds__(256) void k_small_gemm_t(
    const float* __restrict__ A, int a_h, int a_b, int sa0, int sa1,
    const float* __restrict__ B, int b_h, int b_b, int sb0, int sb1,
    void* __restrict__ Cv, int c_h, int c_b, int ldc, int K, float scale) {
  const int bh = blockIdx.x;
  const int b = bh >> 2, h = bh & 3;
  const int m0 = blockIdx.y * 64;
  const float* Ab = A + (size_t)h * a_h + (size_t)b * a_b;
  const float* Bb = B + (size_t)h * b_h + (size_t)b * b_b;

  __shared__ float Ast[16][64];
  __shared__ float Bst[16][DK];
  const int t = threadIdx.x;
  const int tm = t >> 4, tn = t & 15;
  const int mi = tm * 4, nj = tn * 15;
  float acc[4][15];
#pragma unroll
  for (int x = 0; x < 4; ++x)
#pragma unroll
    for (int y = 0; y < 15; ++y) acc[x][y] = 0.f;

  for (int k0 = 0; k0 < K; k0 += 16) {
    __syncthreads();
#pragma unroll
    for (int q = 0; q < 4; ++q) {
      int idx = t + q * 256;
      int m = idx >> 4, k = idx & 15;
      Ast[k][m] = Ab[(size_t)(m0 + m) * sa0 + (size_t)(k0 + k) * sa1];
    }
#pragma unroll
    for (int q = 0; q < 15; ++q) {
      int idx = t + q * 256;
      int k = idx / DK, n = idx - k * DK;
      Bst[k][n] = Bb[(size_t)(k0 + k) * sb0 + (size_t)n * sb1];
    }
    __syncthreads();
#pragma unroll
    for (int kk = 0; kk < 16; ++kk) {
      float a4[4], bn[15];
#pragma unroll
      for (int x = 0; x < 4; ++x) a4[x] = Ast[kk][mi + x];
#pragma unroll
      for (int y = 0; y < 15; ++y) bn[y] = Bst[kk][nj + y];
#pragma unroll
      for (int x = 0; x < 4; ++x)
#pragma unroll
        for (int y = 0; y < 15; ++y) acc[x][y] = fmaf(a4[x], bn[y], acc[x][y]);
    }
  }
  if (BF16OUT) {
    ushort* Cb = (ushort*)Cv + (size_t)h * c_h + (size_t)b * c_b;
#pragma unroll
    for (int x = 0; x < 4; ++x)
#pragma unroll
      for (int y = 0; y < 15; ++y)
        Cb[(size_t)(m0 + mi + x) * ldc + nj + y] = f2bf(acc[x][y] * scale);
  } else {
    float* Cb = (float*)Cv + (size_t)h * c_h + (size_t)b * c_b;
#pragma unroll
    for (int x = 0; x < 4; ++x)
#pragma unroll
      for (int y = 0; y < 15; ++y)
        Cb[(size_t)(m0 + mi + x) * ldc + nj + y] = acc[x][y] * scale;
  }
}

// ---------------------------------------------------------------------------
// InstanceNorm (biased var, eps 1e-5) + softmax over dk.
// ---------------------------------------------------------------------------
__global__ __launch_bounds__(256) void k_inorm_softmax(const float* __restrict__ SC,
                                                       float* __restrict__ PR) {
  const int bh = blockIdx.x;
  const float* s = SC + (size_t)bh * DQ * DK;
  float* p = PR + (size_t)bh * DQ * DK;
  const int t = threadIdx.x;
  float sum = 0.f, sq = 0.f;
  for (int i = t; i < DQ * DK; i += 256) {
    float v = s[i];
    sum += v;
    sq = fmaf(v, v, sq);
  }
#pragma unroll
  for (int o = 32; o > 0; o >>= 1) {
    sum += __shfl_down(sum, o);
    sq += __shfl_down(sq, o);
  }
  __shared__ float s1[4], s2[4];
  if ((t & 63) == 0) { s1[t >> 6] = sum; s2[t >> 6] = sq; }
  __syncthreads();
  const float ts = s1[0] + s1[1] + s1[2] + s1[3];
  const float tq = s2[0] + s2[1] + s2[2] + s2[3];
  const float mu = ts * (1.f / (DQ * DK));
  const float var = tq * (1.f / (DQ * DK)) - mu * mu;
  const float rstd = rsqrtf(var + 1e-5f);
  if (t < DQ) {
    const float* row = s + t * DK;
    float* prow = p + t * DK;
    float m = -1e30f;
    for (int k = 0; k < DK; ++k) m = fmaxf(m, (row[k] - mu) * rstd);
    float acc = 0.f;
    for (int k = 0; k < DK; ++k) {
      float e = __expf((row[k] - mu) * rstd - m);
      prow[k] = e;
      acc += e;
    }
    const float inv = 1.f / acc;
    for (int k = 0; k < DK; ++k) prow[k] *= inv;
  }
}

// ---------------------------------------------------------------------------
// K3 (MFMA): O1[b,n,e] = sum_g embaBF[b,n,g] * W3bf[b,e,g]
// m97 structure: 128x128 tile, BK=32, 4 waves (2x2), global_load_lds w=16.
// grid (32 mt, 4 nt, 8 b), block 256.
// ---------------------------------------------------------------------------
__global__ __launch_bounds__(256) void k3_mfma(const ushort* __restrict__ A,
                                               const ushort* __restrict__ Bw,
                                               float* __restrict__ C) {
  __shared__ ushort As[128 * 32];
  __shared__ ushort Bs[128 * 32];
  const int b = blockIdx.z;
  const int mt = blockIdx.x;
  const int nt = blockIdx.y;
  const int t = threadIdx.x;
  const int w = t >> 6, l = t & 63;
  const int wr = w >> 1, wc = w & 1;

  const ushort* Ab = A + (size_t)b * N_ * KV_ + (size_t)mt * 128 * KV_;
  const ushort* Bb = Bw + (size_t)b * C_ * KV_ + (size_t)nt * 128 * KV_;

  const int r_l = l >> 2;        // staging row within 16-row group
  const int c_l = (l & 3) * 8;   // staging col (elems)

  f32x4 acc[4][4];
#pragma unroll
  for (int fm = 0; fm < 4; ++fm)
#pragma unroll
    for (int fn = 0; fn < 4; ++fn) acc[fm][fn] = (f32x4){0.f, 0.f, 0.f, 0.f};

  const int lrow = l & 15;        // fragment row/col index
  const int lk = (l >> 4) * 8;    // fragment k offset

  for (int k0 = 0; k0 < KV_; k0 += 32) {
#pragma unroll
    for (int inst = 0; inst < 2; ++inst) {
      const int gi = w * 2 + inst;
      const ushort* ga = Ab + (size_t)(gi * 16 + r_l) * KV_ + k0 + c_l;
      __builtin_amdgcn_global_load_lds((AS1 const uint32_t*)(uintptr_t)ga,
                                       (AS3 uint32_t*)(uintptr_t)(As + gi * 512),
                                       16, 0, 0);
      const ushort* gb = Bb + (size_t)(gi * 16 + r_l) * KV_ + k0 + c_l;
      __builtin_amdgcn_global_load_lds((AS1 const uint32_t*)(uintptr_t)gb,
                                       (AS3 uint32_t*)(uintptr_t)(Bs + gi * 512),
                                       16, 0, 0);
    }
    __syncthreads();
    bf16x8 af[4], bfr[4];
#pragma unroll
    for (int fm = 0; fm < 4; ++fm)
      af[fm] = *(const bf16x8*)(As + (wr * 64 + fm * 16 + lrow) * 32 + lk);
#pragma unroll
    for (int fn = 0; fn < 4; ++fn)
      bfr[fn] = *(const bf16x8*)(Bs + (wc * 64 + fn * 16 + lrow) * 32 + lk);
#pragma unroll
    for (int fm = 0; fm < 4; ++fm)
#pragma unroll
      for (int fn = 0; fn < 4; ++fn)
        acc[fm][fn] = __builtin_amdgcn_mfma_f32_16x16x32_bf16(af[fm], bfr[fn],
                                                              acc[fm][fn], 0, 0, 0);
    __syncthreads();
  }

  float* Cb = C + (size_t)b * N_ * C_ + ((size_t)mt * 128) * C_ + nt * 128;
  const int col = wc * 64 + (l & 15);
  const int rbase = wr * 64 + (l >> 4) * 4;
#pragma unroll
  for (int fm = 0; fm < 4; ++fm)
#pragma unroll
    for (int fn = 0; fn < 4; ++fn)
#pragma unroll
      for (int r = 0; r < 4; ++r)
        Cb[(size_t)(rbase + fm * 16 + r) * C_ + col + fn * 16] = acc[fm][fn][r];
}

// ---------------------------------------------------------------------------
// Workspace layout (bytes), total 78,643,200 (same proven footprint as R1):
//   [0, 62914560)          P split-K partials  -> then embaBF (bf16, 62.9MB)
//   [62914560, 66846720)   S (f32)             -> then T (f32)
//   [66846720, 74711040)   U, SC (f32)         -> then W3bf (bf16, 7.86MB)
//   [74711040, 78643200)   PR (f32)
// ---------------------------------------------------------------------------
extern "C" void kernel_launch(void* const* d_in, const int* in_sizes, int n_in,
                              void* d_out, int out_size, void* d_ws, size_t ws_size,
                              hipStream_t stream) {
  const float* emb1 = (const float*)d_in[0];
  const float* emba = (const float*)d_in[1];
  const float* Wq   = (const float*)d_in[2];
  const float* Wk   = (const float*)d_in[3];
  const float* Wv   = (const float*)d_in[4];
  const float* Wo   = (const float*)d_in[5];
  float* out = (float*)d_out;
  char* ws = (char*)d_ws;

  float*  P      = (float*)(ws);
  ushort* embaBF = (ushort*)(ws);
  float*  S      = (float*)(ws + 62914560);
  float*  T      = (float*)(ws + 62914560);
  float*  U      = (float*)(ws + 66846720);
  ushort* W3bf   = (ushort*)(ws + 66846720);
  float*  SCb    = (float*)(ws + 70778880);
  float*  PRb    = (float*)(ws + 74711040);

  // 1) S = sum_n emb1_chunk^T @ emba_chunk (split-K partials + reduce)
  k1_spartial<<<dim3(32, NSPLIT), 256, 0, stream>>>(emb1, emba, P);
  k_reduce<<<960, 256, 0, stream>>>((const float4*)P, (float4*)S);

  // 2) emb_all -> bf16 (P region is dead now)
  k_cvt<<<30720, 256, 0, stream>>>((const float4*)emba, (ushort4*)embaBF, 7864320);

  // 3) U = Wq[h] @ S[b,h]                    (M=128, K=128)
  k_small_gemm_t<false><<<dim3(32, 2), 256, 0, stream>>>(
      Wq, 16384, 0, 128, 1,
      S, 30720, 122880, 240, 1,
      U, 30720, 122880, 240, 128, 1.0f);

  // 4) scores = (U @ Wk^T) / sqrt(960)       (M=128, K=240)
  k_small_gemm_t<false><<<dim3(32, 2), 256, 0, stream>>>(
      U, 30720, 122880, 240, 1,
      Wk, 0, 0, 1, 240,
      SCb, 30720, 122880, 240, 240, 0.0322748612183951f);

  // 5) InstanceNorm + softmax -> probs
  k_inorm_softmax<<<32, 256, 0, stream>>>(SCb, PRb);

  // 6) T = probs @ Wv                        (M=128, K=240)  [S slot dead]
  k_small_gemm_t<false><<<dim3(32, 2), 256, 0, stream>>>(
      PRb, 30720, 122880, 240, 1,
      Wv, 0, 0, 240, 1,
      T, 30720, 122880, 240, 240, 1.0f);

  // 7) W3bf[b,e,h*240+d] = sum_c Wo[e,4c+h] T[c,d]  (M=512, K=128, bf16 out)
  k_small_gemm_t<true><<<dim3(32, 8), 256, 0, stream>>>(
      Wo, 1, 0, 512, 4,
      T, 30720, 122880, 240, 1,
      W3bf, 240, 491520, 960, 128, 1.0f);

  // 8) O1[b] = embaBF[b] @ W3bf[b]^T  (MFMA)
  k3_mfma<<<dim3(32, 4, 8), 256, 0, stream>>>(embaBF, W3bf, out);
}

// Round 3
// 369.873 us; speedup vs baseline: 2.2884x; 1.5129x over previous
//
#include <hip/hip_runtime.h>
#include <cstdint>
#include <cstddef>

#define B_ 8
#define N_ 4096
#define C_ 512
#define KV_ 960
#define DQ 128
#define DK 240
#define NSPLIT 8   // split-K over n for k1: 256 blocks = 1/CU

typedef __attribute__((ext_vector_type(8))) short bf16x8;
typedef __attribute__((ext_vector_type(4))) float f32x4;
#define AS1 __attribute__((address_space(1)))
#define AS3 __attribute__((address_space(3)))

__device__ __forceinline__ ushort f2bf(float f) {
  uint32_t u = __float_as_uint(f);
  u += 0x7FFFu + ((u >> 16) & 1u);  // RNE
  return (ushort)(u >> 16);
}

// ---------------------------------------------------------------------------
// K1 (MFMA): partial S[b,h,i,j] = sum_{n in split} emb1[b,n,h*128+i]*emba[b,n,h*240+j]
// TN GEMM: per (b,h) tile M=128(i) x N=256(j, 240 valid) x K=512 n per split.
// Gather-staged transpose: coalesced scalar f32 column loads -> bf16 ->
// ds_write_b128 of k-contiguous rows. 16B-granular XOR swizzle on both sides.
// Partials stored fragment-native (f32x4, [v][t]) fully coalesced.
// grid (32 bh, NSPLIT), block 512 (8 waves, 2x4 -> wave tile 64x64).
// ---------------------------------------------------------------------------
__global__ __launch_bounds__(512) void k1_mfma(const float* __restrict__ emb1,
                                               const float* __restrict__ emba,
                                               float* __restrict__ P) {
  __shared__ ushort As[128 * 64];  // [i=128][n=64], 8-elem blocks swizzled
  __shared__ ushort Bs[256 * 64];  // [j=256][n=64], swizzled
  const int bh = blockIdx.x;
  const int split = blockIdx.y;
  const int b = bh >> 2, h = bh & 3;
  const int t = threadIdx.x;
  const int w = t >> 6, l = t & 63;
  const int wr = w >> 2, wc = w & 3;  // wave tile: rows wr*64, cols wc*64

  const float* Abase = emb1 + (size_t)b * N_ * C_ + h * DQ;  // + n*C_ + c
  const float* Bbase = emba + (size_t)b * N_ * KV_;          // + n*KV_ + jg

  // A gather: column c, 2 n-blocks per K-step
  const int cA = t & 127;
  const int nbA0 = t >> 7;  // 0..3
  // B gather: column j (clamped into valid emba range), 4 n-blocks per K-step
  const int jB = t & 255;
  int jg = h * DK + jB;
  if (jg > KV_ - 1) jg = KV_ - 1;  // padded cols: duplicate last col (discarded)
  const int nbB0 = t >> 8;  // 0..1

  f32x4 acc[4][4];
#pragma unroll
  for (int fm = 0; fm < 4; ++fm)
#pragma unroll
    for (int fn = 0; fn < 4; ++fn) acc[fm][fn] = (f32x4){0.f, 0.f, 0.f, 0.f};

  const int n0 = split * (N_ / NSPLIT);
  const int lrow = l & 15;

  for (int ks = 0; ks < (N_ / NSPLIT) / 64; ++ks) {
    const int nb0 = n0 + ks * 64;
    __syncthreads();
    // --- stage A: 1024 b128 writes, 2 per thread ---
#pragma unroll
    for (int q = 0; q < 2; ++q) {
      const int nb = nbA0 + q * 4;  // 0..7
      const float* g = Abase + (size_t)(nb0 + nb * 8) * C_ + cA;
      float v[8];
#pragma unroll
      for (int kk = 0; kk < 8; ++kk) v[kk] = g[(size_t)kk * C_];
      bf16x8 pk;
#pragma unroll
      for (int kk = 0; kk < 8; ++kk) pk[kk] = (short)f2bf(v[kk]);
      *(bf16x8*)(As + cA * 64 + ((nb ^ (cA & 7)) << 3)) = pk;
    }
    // --- stage B: 2048 b128 writes, 4 per thread ---
#pragma unroll
    for (int q = 0; q < 4; ++q) {
      const int nb = nbB0 + q * 2;  // 0..7
      const float* g = Bbase + (size_t)(nb0 + nb * 8) * KV_ + jg;
      float v[8];
#pragma unroll
      for (int kk = 0; kk < 8; ++kk) v[kk] = g[(size_t)kk * KV_];
      bf16x8 pk;
#pragma unroll
      for (int kk = 0; kk < 8; ++kk) pk[kk] = (short)f2bf(v[kk]);
      *(bf16x8*)(Bs + jB * 64 + ((nb ^ (jB & 7)) << 3)) = pk;
    }
    __syncthreads();
    // --- MFMA: 2 k-halves x 4x4 fragments ---
#pragma unroll
    for (int ks2 = 0; ks2 < 2; ++ks2) {
      const int kb = ks2 * 4 + (l >> 4);  // n-block 0..7
      bf16x8 af[4], bv[4];
#pragma unroll
      for (int fm = 0; fm < 4; ++fm) {
        const int i = wr * 64 + fm * 16 + lrow;
        af[fm] = *(const bf16x8*)(As + i * 64 + ((kb ^ (i & 7)) << 3));
      }
#pragma unroll
      for (int fn = 0; fn < 4; ++fn) {
        const int j = wc * 64 + fn * 16 + lrow;
        bv[fn] = *(const bf16x8*)(Bs + j * 64 + ((kb ^ (j & 7)) << 3));
      }
#pragma unroll
      for (int fm = 0; fm < 4; ++fm)
#pragma unroll
        for (int fn = 0; fn < 4; ++fn)
          acc[fm][fn] = __builtin_amdgcn_mfma_f32_16x16x32_bf16(af[fm], bv[fn],
                                                                acc[fm][fn], 0, 0, 0);
    }
  }
  // fragment-native coalesced store: P[split][bh][v=fm*4+fn][t] (f32x4)
  f32x4* Pv4 = (f32x4*)P + (size_t)(split * 32 + bh) * 8192;
#pragma unroll
  for (int fm = 0; fm < 4; ++fm)
#pragma unroll
    for (int fn = 0; fn < 4; ++fn) Pv4[(fm * 4 + fn) * 512 + t] = acc[fm][fn];
}

// ---------------------------------------------------------------------------
// Reduce NSPLIT fragment-native partials and un-swizzle into S[bh][128][240].
// grid (32 bh, 32), block 256.
// ---------------------------------------------------------------------------
__global__ __launch_bounds__(256) void k_reduce_frag(const f32x4* __restrict__ P,
                                                     float* __restrict__ S) {
  const int bh = blockIdx.x;
  const int g = blockIdx.y * 256 + threadIdx.x;  // 0..8191
  f32x4 a = P[(size_t)bh * 8192 + g];
#pragma unroll
  for (int s = 1; s < NSPLIT; ++s) {
    f32x4 v = P[(size_t)s * 262144 + (size_t)bh * 8192 + g];
    a.x += v.x; a.y += v.y; a.z += v.z; a.w += v.w;
  }
  const int v = g >> 9, tt = g & 511;
  const int fm = v >> 2, fn = v & 3;
  const int wv = tt >> 6, l = tt & 63;
  const int wr = wv >> 2, wc = wv & 3;
  const int i0 = wr * 64 + fm * 16 + (l >> 4) * 4;
  const int j = wc * 64 + fn * 16 + (l & 15);
  if (j < DK) {
    float* sp = S + (size_t)bh * (DQ * DK) + (size_t)i0 * DK + j;
    sp[0] = a.x; sp[DK] = a.y; sp[2 * DK] = a.z; sp[3 * DK] = a.w;
  }
}

// ---------------------------------------------------------------------------
// f32 -> bf16 (RNE), 4 elems/thread
// ---------------------------------------------------------------------------
__global__ __launch_bounds__(256) void k_cvt(const float4* __restrict__ in,
                                             ushort4* __restrict__ out, int n4) {
  int i = blockIdx.x * 256 + threadIdx.x;
  if (i >= n4) return;
  float4 v = in[i];
  ushort4 o;
  o.x = f2bf(v.x); o.y = f2bf(v.y); o.z = f2bf(v.z); o.w = f2bf(v.w);
  out[i] = o;
}

// ---------------------------------------------------------------------------
// Generic small GEMM over the 32 (b,h) problems, N fixed 240.
// ---------------------------------------------------------------------------
template <bool BF16OUT>
__global__ __launch_bounds__(256) void k_small_gemm_t(
    const float* __restrict__ A, int a_h, int a_b, int sa0, int sa1,
    const float* __restrict__ B, int b_h, int b_b, int sb0, int sb1,
    void* __restrict__ Cv, int c_h, int c_b, int ldc, int K, float scale) {
  const int bh = blockIdx.x;
  const int b = bh >> 2, h = bh & 3;
  const int m0 = blockIdx.y * 64;
  const float* Ab = A + (size_t)h * a_h + (size_t)b * a_b;
  const float* Bb = B + (size_t)h * b_h + (size_t)b * b_b;

  __shared__ float Ast[16][64];
  __shared__ float Bst[16][DK];
  const int t = threadIdx.x;
  const int tm = t >> 4, tn = t & 15;
  const int mi = tm * 4, nj = tn * 15;
  float acc[4][15];
#pragma unroll
  for (int x = 0; x < 4; ++x)
#pragma unroll
    for (int y = 0; y < 15; ++y) acc[x][y] = 0.f;

  for (int k0 = 0; k0 < K; k0 += 16) {
    __syncthreads();
#pragma unroll
    for (int q = 0; q < 4; ++q) {
      int idx = t + q * 256;
      int m = idx >> 4, k = idx & 15;
      Ast[k][m] = Ab[(size_t)(m0 + m) * sa0 + (size_t)(k0 + k) * sa1];
    }
#pragma unroll
    for (int q = 0; q < 15; ++q) {
      int idx = t + q * 256;
      int k = idx / DK, n = idx - k * DK;
      Bst[k][n] = Bb[(size_t)(k0 + k) * sb0 + (size_t)n * sb1];
    }
    __syncthreads();
#pragma unroll
    for (int kk = 0; kk < 16; ++kk) {
      float a4[4], bn[15];
#pragma unroll
      for (int x = 0; x < 4; ++x) a4[x] = Ast[kk][mi + x];
#pragma unroll
      for (int y = 0; y < 15; ++y) bn[y] = Bst[kk][nj + y];
#pragma unroll
      for (int x = 0; x < 4; ++x)
#pragma unroll
        for (int y = 0; y < 15; ++y) acc[x][y] = fmaf(a4[x], bn[y], acc[x][y]);
    }
  }
  if (BF16OUT) {
    ushort* Cb = (ushort*)Cv + (size_t)h * c_h + (size_t)b * c_b;
#pragma unroll
    for (int x = 0; x < 4; ++x)
#pragma unroll
      for (int y = 0; y < 15; ++y)
        Cb[(size_t)(m0 + mi + x) * ldc + nj + y] = f2bf(acc[x][y] * scale);
  } else {
    float* Cb = (float*)Cv + (size_t)h * c_h + (size_t)b * c_b;
#pragma unroll
    for (int x = 0; x < 4; ++x)
#pragma unroll
      for (int y = 0; y < 15; ++y)
        Cb[(size_t)(m0 + mi + x) * ldc + nj + y] = acc[x][y] * scale;
  }
}

// ---------------------------------------------------------------------------
// InstanceNorm (biased var, eps 1e-5) + softmax over dk.
// ---------------------------------------------------------------------------
__global__ __launch_bounds__(256) void k_inorm_softmax(const float* __restrict__ SC,
                                                       float* __restrict__ PR) {
  const int bh = blockIdx.x;
  const float* s = SC + (size_t)bh * DQ * DK;
  float* p = PR + (size_t)bh * DQ * DK;
  const int t = threadIdx.x;
  float sum = 0.f, sq = 0.f;
  for (int i = t; i < DQ * DK; i += 256) {
    float v = s[i];
    sum += v;
    sq = fmaf(v, v, sq);
  }
#pragma unroll
  for (int o = 32; o > 0; o >>= 1) {
    sum += __shfl_down(sum, o);
    sq += __shfl_down(sq, o);
  }
  __shared__ float s1[4], s2[4];
  if ((t & 63) == 0) { s1[t >> 6] = sum; s2[t >> 6] = sq; }
  __syncthreads();
  const float ts = s1[0] + s1[1] + s1[2] + s1[3];
  const float tq = s2[0] + s2[1] + s2[2] + s2[3];
  const float mu = ts * (1.f / (DQ * DK));
  const float var = tq * (1.f / (DQ * DK)) - mu * mu;
  const float rstd = rsqrtf(var + 1e-5f);
  if (t < DQ) {
    const float* row = s + t * DK;
    float* prow = p + t * DK;
    float m = -1e30f;
    for (int k = 0; k < DK; ++k) m = fmaxf(m, (row[k] - mu) * rstd);
    float acc = 0.f;
    for (int k = 0; k < DK; ++k) {
      float e = __expf((row[k] - mu) * rstd - m);
      prow[k] = e;
      acc += e;
    }
    const float inv = 1.f / acc;
    for (int k = 0; k < DK; ++k) prow[k] *= inv;
  }
}

// ---------------------------------------------------------------------------
// K3 (MFMA): O1[b,n,e] = sum_g embaBF[b,n,g] * W3bf[b,e,g]
// m97 structure: 128x128 tile, BK=32, 4 waves (2x2), global_load_lds w=16.
// ---------------------------------------------------------------------------
__global__ __launch_bounds__(256) void k3_mfma(const ushort* __restrict__ A,
                                               const ushort* __restrict__ Bw,
                                               float* __restrict__ C) {
  __shared__ ushort As[128 * 32];
  __shared__ ushort Bs[128 * 32];
  const int b = blockIdx.z;
  const int mt = blockIdx.x;
  const int nt = blockIdx.y;
  const int t = threadIdx.x;
  const int w = t >> 6, l = t & 63;
  const int wr = w >> 1, wc = w & 1;

  const ushort* Ab = A + (size_t)b * N_ * KV_ + (size_t)mt * 128 * KV_;
  const ushort* Bb = Bw + (size_t)b * C_ * KV_ + (size_t)nt * 128 * KV_;

  const int r_l = l >> 2;
  const int c_l = (l & 3) * 8;

  f32x4 acc[4][4];
#pragma unroll
  for (int fm = 0; fm < 4; ++fm)
#pragma unroll
    for (int fn = 0; fn < 4; ++fn) acc[fm][fn] = (f32x4){0.f, 0.f, 0.f, 0.f};

  const int lrow = l & 15;
  const int lk = (l >> 4) * 8;

  for (int k0 = 0; k0 < KV_; k0 += 32) {
#pragma unroll
    for (int inst = 0; inst < 2; ++inst) {
      const int gi = w * 2 + inst;
      const ushort* ga = Ab + (size_t)(gi * 16 + r_l) * KV_ + k0 + c_l;
      __builtin_amdgcn_global_load_lds((AS1 const uint32_t*)(uintptr_t)ga,
                                       (AS3 uint32_t*)(uintptr_t)(As + gi * 512),
                                       16, 0, 0);
      const ushort* gb = Bb + (size_t)(gi * 16 + r_l) * KV_ + k0 + c_l;
      __builtin_amdgcn_global_load_lds((AS1 const uint32_t*)(uintptr_t)gb,
                                       (AS3 uint32_t*)(uintptr_t)(Bs + gi * 512),
                                       16, 0, 0);
    }
    __syncthreads();
    bf16x8 af[4], bfr[4];
#pragma unroll
    for (int fm = 0; fm < 4; ++fm)
      af[fm] = *(const bf16x8*)(As + (wr * 64 + fm * 16 + lrow) * 32 + lk);
#pragma unroll
    for (int fn = 0; fn < 4; ++fn)
      bfr[fn] = *(const bf16x8*)(Bs + (wc * 64 + fn * 16 + lrow) * 32 + lk);
#pragma unroll
    for (int fm = 0; fm < 4; ++fm)
#pragma unroll
      for (int fn = 0; fn < 4; ++fn)
        acc[fm][fn] = __builtin_amdgcn_mfma_f32_16x16x32_bf16(af[fm], bfr[fn],
                                                              acc[fm][fn], 0, 0, 0);
    __syncthreads();
  }

  float* Cb = C + (size_t)b * N_ * C_ + ((size_t)mt * 128) * C_ + nt * 128;
  const int col = wc * 64 + (l & 15);
  const int rbase = wr * 64 + (l >> 4) * 4;
#pragma unroll
  for (int fm = 0; fm < 4; ++fm)
#pragma unroll
    for (int fn = 0; fn < 4; ++fn)
#pragma unroll
      for (int r = 0; r < 4; ++r)
        Cb[(size_t)(rbase + fm * 16 + r) * C_ + col + fn * 16] = acc[fm][fn][r];
}

// ---------------------------------------------------------------------------
// Workspace layout (bytes), total 78,643,200 (same proven footprint):
//   [0, 33554432)          P frag-partials (f32) -> dead after reduce
//   [0, 62914560)          embaBF (bf16) after reduce
//   [62914560, 66846720)   S (f32) -> then T (f32)
//   [66846720, 74711040)   U, SC (f32) -> then W3bf (bf16)
//   [74711040, 78643200)   PR (f32)
// ---------------------------------------------------------------------------
extern "C" void kernel_launch(void* const* d_in, const int* in_sizes, int n_in,
                              void* d_out, int out_size, void* d_ws, size_t ws_size,
                              hipStream_t stream) {
  const float* emb1 = (const float*)d_in[0];
  const float* emba = (const float*)d_in[1];
  const float* Wq   = (const float*)d_in[2];
  const float* Wk   = (const float*)d_in[3];
  const float* Wv   = (const float*)d_in[4];
  const float* Wo   = (const float*)d_in[5];
  float* out = (float*)d_out;
  char* ws = (char*)d_ws;

  float*  P      = (float*)(ws);
  ushort* embaBF = (ushort*)(ws);
  float*  S      = (float*)(ws + 62914560);
  float*  T      = (float*)(ws + 62914560);
  float*  U      = (float*)(ws + 66846720);
  ushort* W3bf   = (ushort*)(ws + 66846720);
  float*  SCb    = (float*)(ws + 70778880);
  float*  PRb    = (float*)(ws + 74711040);

  // 1) S partials (MFMA, fragment-native) + reduce/unswizzle
  k1_mfma<<<dim3(32, NSPLIT), 512, 0, stream>>>(emb1, emba, P);
  k_reduce_frag<<<dim3(32, 32), 256, 0, stream>>>((const f32x4*)P, S);

  // 2) emb_all -> bf16 (P region is dead now)
  k_cvt<<<30720, 256, 0, stream>>>((const float4*)emba, (ushort4*)embaBF, 7864320);

  // 3) U = Wq[h] @ S[b,h]                    (M=128, K=128)
  k_small_gemm_t<false><<<dim3(32, 2), 256, 0, stream>>>(
      Wq, 16384, 0, 128, 1,
      S, 30720, 122880, 240, 1,
      U, 30720, 122880, 240, 128, 1.0f);

  // 4) scores = (U @ Wk^T) / sqrt(960)       (M=128, K=240)
  k_small_gemm_t<false><<<dim3(32, 2), 256, 0, stream>>>(
      U, 30720, 122880, 240, 1,
      Wk, 0, 0, 1, 240,
      SCb, 30720, 122880, 240, 240, 0.0322748612183951f);

  // 5) InstanceNorm + softmax -> probs
  k_inorm_softmax<<<32, 256, 0, stream>>>(SCb, PRb);

  // 6) T = probs @ Wv                        (M=128, K=240)
  k_small_gemm_t<false><<<dim3(32, 2), 256, 0, stream>>>(
      PRb, 30720, 122880, 240, 1,
      Wv, 0, 0, 240, 1,
      T, 30720, 122880, 240, 240, 1.0f);

  // 7) W3bf[b,e,h*240+d] = sum_c Wo[e,4c+h] T[c,d]  (M=512, K=128, bf16 out)
  k_small_gemm_t<true><<<dim3(32, 8), 256, 0, stream>>>(
      Wo, 1, 0, 512, 4,
      T, 30720, 122880, 240, 1,
      W3bf, 240, 491520, 960, 128, 1.0f);

  // 8) O1[b] = embaBF[b] @ W3bf[b]^T  (MFMA)
  k3_mfma<<<dim3(32, 4, 8), 256, 0, stream>>>(embaBF, W3bf, out);
}

// Round 4
// 354.529 us; speedup vs baseline: 2.3874x; 1.0433x over previous
//
#include <hip/hip_runtime.h>
#include <cstdint>
#include <cstddef>

#define B_ 8
#define N_ 4096
#define C_ 512
#define KV_ 960
#define DQ 128
#define DK 240
#define NSPLIT 8   // split-K over n for k1: 256 blocks = 1/CU

typedef __attribute__((ext_vector_type(8))) short bf16x8;
typedef __attribute__((ext_vector_type(4))) float f32x4;
#define AS1 __attribute__((address_space(1)))
#define AS3 __attribute__((address_space(3)))

__device__ __forceinline__ ushort f2bf(float f) {
  uint32_t u = __float_as_uint(f);
  u += 0x7FFFu + ((u >> 16) & 1u);  // RNE
  return (ushort)(u >> 16);
}

__device__ __forceinline__ uint32_t cvtpk(float lo, float hi) {
  uint32_t r;
  asm("v_cvt_pk_bf16_f32 %0, %1, %2" : "=v"(r) : "v"(lo), "v"(hi));
  return r;
}

union bfpack {
  uint32_t u[4];
  bf16x8 v;
};

// ---------------------------------------------------------------------------
// K1 (MFMA, register-pipelined): partial
//   S[b,h,i,j] = sum_{n in split} emb1[b,n,h*128+i] * emba[b,n,h*240+j]
// Per (b,h): M=128(i) x N=256(j; 240 valid) x K=512 n per split, BK=64.
// Pipeline per K-step (raw barriers, loads stay in flight across them):
//   pack(regs) | s_barrier | ds_write | issue loads(ks+1) | lgkmcnt(0)
//   | s_barrier | ds_read+MFMA
// grid (32 bh, NSPLIT), block 512 (8 waves, 2x4 -> wave tile 64x64).
// ---------------------------------------------------------------------------
__global__ __launch_bounds__(512) void k1_mfma(const float* __restrict__ emb1,
                                               const float* __restrict__ emba,
                                               float* __restrict__ P) {
  __shared__ ushort As[128 * 64];  // [i=128][n=64], 8-elem blocks XOR-swizzled
  __shared__ ushort Bs[256 * 64];  // [j=256][n=64], swizzled
  const int bh = blockIdx.x;
  const int split = blockIdx.y;
  const int b = bh >> 2, h = bh & 3;
  const int t = threadIdx.x;
  const int w = t >> 6, l = t & 63;
  const int wr = w >> 2, wc = w & 3;  // wave tile: rows wr*64, cols wc*64

  const float* Abase = emb1 + (size_t)b * N_ * C_ + h * DQ;  // + n*C_ + c
  const float* Bbase = emba + (size_t)b * N_ * KV_;          // + n*KV_ + jg

  const int cA = t & 127;   // A gather column
  const int nbA0 = t >> 7;  // 0..3
  const int jB = t & 255;   // B gather column (padded)
  int jg = h * DK + jB;
  if (jg > KV_ - 1) jg = KV_ - 1;  // padded cols duplicate last col (discarded)
  const int nbB0 = t >> 8;  // 0..1

  f32x4 acc[4][4];
#pragma unroll
  for (int fm = 0; fm < 4; ++fm)
#pragma unroll
    for (int fn = 0; fn < 4; ++fn) acc[fm][fn] = (f32x4){0.f, 0.f, 0.f, 0.f};

  const int n0 = split * (N_ / NSPLIT);
  const int lrow = l & 15;
  const int KS = (N_ / NSPLIT) / 64;  // 8

  float va[2][8], vb[4][8];

  // prologue: issue loads for tile 0
#pragma unroll
  for (int q = 0; q < 2; ++q) {
    const float* g = Abase + (size_t)(n0 + (nbA0 + q * 4) * 8) * C_ + cA;
#pragma unroll
    for (int kk = 0; kk < 8; ++kk) va[q][kk] = g[(size_t)kk * C_];
  }
#pragma unroll
  for (int q = 0; q < 4; ++q) {
    const float* g = Bbase + (size_t)(n0 + (nbB0 + q * 2) * 8) * KV_ + jg;
#pragma unroll
    for (int kk = 0; kk < 8; ++kk) vb[q][kk] = g[(size_t)kk * KV_];
  }

  for (int ks = 0; ks < KS; ++ks) {
    // pack current regs -> bf16 (compiler inserts vmcnt waits here)
    bfpack pa[2], pb[4];
#pragma unroll
    for (int q = 0; q < 2; ++q)
#pragma unroll
      for (int p = 0; p < 4; ++p) pa[q].u[p] = cvtpk(va[q][2 * p], va[q][2 * p + 1]);
#pragma unroll
    for (int q = 0; q < 4; ++q)
#pragma unroll
      for (int p = 0; p < 4; ++p) pb[q].u[p] = cvtpk(vb[q][2 * p], vb[q][2 * p + 1]);

    // barrier 1: previous MFMA phase's ds_reads complete (data-dep lgkm waits)
    __builtin_amdgcn_s_barrier();

    // stage to LDS (swizzled)
#pragma unroll
    for (int q = 0; q < 2; ++q) {
      const int nb = nbA0 + q * 4;
      *(bf16x8*)(As + cA * 64 + ((nb ^ (cA & 7)) << 3)) = pa[q].v;
    }
#pragma unroll
    for (int q = 0; q < 4; ++q) {
      const int nb = nbB0 + q * 2;
      *(bf16x8*)(Bs + jB * 64 + ((nb ^ (jB & 7)) << 3)) = pb[q].v;
    }

    // issue next tile's global loads; they stay in flight through the MFMA phase
    if (ks + 1 < KS) {
      const int nb1 = n0 + (ks + 1) * 64;
#pragma unroll
      for (int q = 0; q < 2; ++q) {
        const float* g = Abase + (size_t)(nb1 + (nbA0 + q * 4) * 8) * C_ + cA;
#pragma unroll
        for (int kk = 0; kk < 8; ++kk) va[q][kk] = g[(size_t)kk * C_];
      }
#pragma unroll
      for (int q = 0; q < 4; ++q) {
        const float* g = Bbase + (size_t)(nb1 + (nbB0 + q * 2) * 8) * KV_ + jg;
#pragma unroll
        for (int kk = 0; kk < 8; ++kk) vb[q][kk] = g[(size_t)kk * KV_];
      }
    }

    // drain DS writes only (global loads keep flying), then barrier 2
    asm volatile("s_waitcnt lgkmcnt(0)" ::: "memory");
    __builtin_amdgcn_sched_barrier(0);
    __builtin_amdgcn_s_barrier();

    // MFMA phase: 2 k-halves x 4x4 fragments
#pragma unroll
    for (int ks2 = 0; ks2 < 2; ++ks2) {
      const int kb = ks2 * 4 + (l >> 4);  // n-block 0..7
      bf16x8 af[4], bv[4];
#pragma unroll
      for (int fm = 0; fm < 4; ++fm) {
        const int i = wr * 64 + fm * 16 + lrow;
        af[fm] = *(const bf16x8*)(As + i * 64 + ((kb ^ (i & 7)) << 3));
      }
#pragma unroll
      for (int fn = 0; fn < 4; ++fn) {
        const int j = wc * 64 + fn * 16 + lrow;
        bv[fn] = *(const bf16x8*)(Bs + j * 64 + ((kb ^ (j & 7)) << 3));
      }
#pragma unroll
      for (int fm = 0; fm < 4; ++fm)
#pragma unroll
        for (int fn = 0; fn < 4; ++fn)
          acc[fm][fn] = __builtin_amdgcn_mfma_f32_16x16x32_bf16(af[fm], bv[fn],
                                                                acc[fm][fn], 0, 0, 0);
    }
  }
  // fragment-native coalesced store: P[split][bh][v=fm*4+fn][t] (f32x4)
  f32x4* Pv4 = (f32x4*)P + (size_t)(split * 32 + bh) * 8192;
#pragma unroll
  for (int fm = 0; fm < 4; ++fm)
#pragma unroll
    for (int fn = 0; fn < 4; ++fn) Pv4[(fm * 4 + fn) * 512 + t] = acc[fm][fn];
}

// ---------------------------------------------------------------------------
// Reduce NSPLIT fragment-native partials and un-swizzle into S[bh][128][240].
// grid (32 bh, 32), block 256.
// ---------------------------------------------------------------------------
__global__ __launch_bounds__(256) void k_reduce_frag(const f32x4* __restrict__ P,
                                                     float* __restrict__ S) {
  const int bh = blockIdx.x;
  const int g = blockIdx.y * 256 + threadIdx.x;  // 0..8191
  f32x4 a = P[(size_t)bh * 8192 + g];
#pragma unroll
  for (int s = 1; s < NSPLIT; ++s) {
    f32x4 v = P[(size_t)s * 262144 + (size_t)bh * 8192 + g];
    a.x += v.x; a.y += v.y; a.z += v.z; a.w += v.w;
  }
  const int v = g >> 9, tt = g & 511;
  const int fm = v >> 2, fn = v & 3;
  const int wv = tt >> 6, l = tt & 63;
  const int wr = wv >> 2, wc = wv & 3;
  const int i0 = wr * 64 + fm * 16 + (l >> 4) * 4;
  const int j = wc * 64 + fn * 16 + (l & 15);
  if (j < DK) {
    float* sp = S + (size_t)bh * (DQ * DK) + (size_t)i0 * DK + j;
    sp[0] = a.x; sp[DK] = a.y; sp[2 * DK] = a.z; sp[3 * DK] = a.w;
  }
}

// ---------------------------------------------------------------------------
// f32 -> bf16 (RNE), 4 elems/thread
// ---------------------------------------------------------------------------
__global__ __launch_bounds__(256) void k_cvt(const float4* __restrict__ in,
                                             ushort4* __restrict__ out, int n4) {
  int i = blockIdx.x * 256 + threadIdx.x;
  if (i >= n4) return;
  float4 v = in[i];
  ushort4 o;
  o.x = f2bf(v.x); o.y = f2bf(v.y); o.z = f2bf(v.z); o.w = f2bf(v.w);
  out[i] = o;
}

// ---------------------------------------------------------------------------
// Generic small GEMM over the 32 (b,h) problems, N fixed 240.
// ---------------------------------------------------------------------------
template <bool BF16OUT>
__global__ __launch_bounds__(256) void k_small_gemm_t(
    const float* __restrict__ A, int a_h, int a_b, int sa0, int sa1,
    const float* __restrict__ B, int b_h, int b_b, int sb0, int sb1,
    void* __restrict__ Cv, int c_h, int c_b, int ldc, int K, float scale) {
  const int bh = blockIdx.x;
  const int b = bh >> 2, h = bh & 3;
  const int m0 = blockIdx.y * 64;
  const float* Ab = A + (size_t)h * a_h + (size_t)b * a_b;
  const float* Bb = B + (size_t)h * b_h + (size_t)b * b_b;

  __shared__ float Ast[16][64];
  __shared__ float Bst[16][DK];
  const int t = threadIdx.x;
  const int tm = t >> 4, tn = t & 15;
  const int mi = tm * 4, nj = tn * 15;
  float acc[4][15];
#pragma unroll
  for (int x = 0; x < 4; ++x)
#pragma unroll
    for (int y = 0; y < 15; ++y) acc[x][y] = 0.f;

  for (int k0 = 0; k0 < K; k0 += 16) {
    __syncthreads();
#pragma unroll
    for (int q = 0; q < 4; ++q) {
      int idx = t + q * 256;
      int m = idx >> 4, k = idx & 15;
      Ast[k][m] = Ab[(size_t)(m0 + m) * sa0 + (size_t)(k0 + k) * sa1];
    }
#pragma unroll
    for (int q = 0; q < 15; ++q) {
      int idx = t + q * 256;
      int k = idx / DK, n = idx - k * DK;
      Bst[k][n] = Bb[(size_t)(k0 + k) * sb0 + (size_t)n * sb1];
    }
    __syncthreads();
#pragma unroll
    for (int kk = 0; kk < 16; ++kk) {
      float a4[4], bn[15];
#pragma unroll
      for (int x = 0; x < 4; ++x) a4[x] = Ast[kk][mi + x];
#pragma unroll
      for (int y = 0; y < 15; ++y) bn[y] = Bst[kk][nj + y];
#pragma unroll
      for (int x = 0; x < 4; ++x)
#pragma unroll
        for (int y = 0; y < 15; ++y) acc[x][y] = fmaf(a4[x], bn[y], acc[x][y]);
    }
  }
  if (BF16OUT) {
    ushort* Cb = (ushort*)Cv + (size_t)h * c_h + (size_t)b * c_b;
#pragma unroll
    for (int x = 0; x < 4; ++x)
#pragma unroll
      for (int y = 0; y < 15; ++y)
        Cb[(size_t)(m0 + mi + x) * ldc + nj + y] = f2bf(acc[x][y] * scale);
  } else {
    float* Cb = (float*)Cv + (size_t)h * c_h + (size_t)b * c_b;
#pragma unroll
    for (int x = 0; x < 4; ++x)
#pragma unroll
      for (int y = 0; y < 15; ++y)
        Cb[(size_t)(m0 + mi + x) * ldc + nj + y] = acc[x][y] * scale;
  }
}

// ---------------------------------------------------------------------------
// InstanceNorm (biased var, eps 1e-5) + softmax over dk.
// ---------------------------------------------------------------------------
__global__ __launch_bounds__(256) void k_inorm_softmax(const float* __restrict__ SC,
                                                       float* __restrict__ PR) {
  const int bh = blockIdx.x;
  const float* s = SC + (size_t)bh * DQ * DK;
  float* p = PR + (size_t)bh * DQ * DK;
  const int t = threadIdx.x;
  float sum = 0.f, sq = 0.f;
  for (int i = t; i < DQ * DK; i += 256) {
    float v = s[i];
    sum += v;
    sq = fmaf(v, v, sq);
  }
#pragma unroll
  for (int o = 32; o > 0; o >>= 1) {
    sum += __shfl_down(sum, o);
    sq += __shfl_down(sq, o);
  }
  __shared__ float s1[4], s2[4];
  if ((t & 63) == 0) { s1[t >> 6] = sum; s2[t >> 6] = sq; }
  __syncthreads();
  const float ts = s1[0] + s1[1] + s1[2] + s1[3];
  const float tq = s2[0] + s2[1] + s2[2] + s2[3];
  const float mu = ts * (1.f / (DQ * DK));
  const float var = tq * (1.f / (DQ * DK)) - mu * mu;
  const float rstd = rsqrtf(var + 1e-5f);
  if (t < DQ) {
    const float* row = s + t * DK;
    float* prow = p + t * DK;
    float m = -1e30f;
    for (int k = 0; k < DK; ++k) m = fmaxf(m, (row[k] - mu) * rstd);
    float acc = 0.f;
    for (int k = 0; k < DK; ++k) {
      float e = __expf((row[k] - mu) * rstd - m);
      prow[k] = e;
      acc += e;
    }
    const float inv = 1.f / acc;
    for (int k = 0; k < DK; ++k) prow[k] *= inv;
  }
}

// ---------------------------------------------------------------------------
// K3 (MFMA): O1[b,n,e] = sum_g embaBF[b,n,g] * W3bf[b,e,g]
// m97 structure: 128x128 tile, BK=32, 4 waves (2x2), global_load_lds w=16.
// ---------------------------------------------------------------------------
__global__ __launch_bounds__(256) void k3_mfma(const ushort* __restrict__ A,
                                               const ushort* __restrict__ Bw,
                                               float* __restrict__ C) {
  __shared__ ushort As[128 * 32];
  __shared__ ushort Bs[128 * 32];
  const int b = blockIdx.z;
  const int mt = blockIdx.x;
  const int nt = blockIdx.y;
  const int t = threadIdx.x;
  const int w = t >> 6, l = t & 63;
  const int wr = w >> 1, wc = w & 1;

  const ushort* Ab = A + (size_t)b * N_ * KV_ + (size_t)mt * 128 * KV_;
  const ushort* Bb = Bw + (size_t)b * C_ * KV_ + (size_t)nt * 128 * KV_;

  const int r_l = l >> 2;
  const int c_l = (l & 3) * 8;

  f32x4 acc[4][4];
#pragma unroll
  for (int fm = 0; fm < 4; ++fm)
#pragma unroll
    for (int fn = 0; fn < 4; ++fn) acc[fm][fn] = (f32x4){0.f, 0.f, 0.f, 0.f};

  const int lrow = l & 15;
  const int lk = (l >> 4) * 8;

  for (int k0 = 0; k0 < KV_; k0 += 32) {
#pragma unroll
    for (int inst = 0; inst < 2; ++inst) {
      const int gi = w * 2 + inst;
      const ushort* ga = Ab + (size_t)(gi * 16 + r_l) * KV_ + k0 + c_l;
      __builtin_amdgcn_global_load_lds((AS1 const uint32_t*)(uintptr_t)ga,
                                       (AS3 uint32_t*)(uintptr_t)(As + gi * 512),
                                       16, 0, 0);
      const ushort* gb = Bb + (size_t)(gi * 16 + r_l) * KV_ + k0 + c_l;
      __builtin_amdgcn_global_load_lds((AS1 const uint32_t*)(uintptr_t)gb,
                                       (AS3 uint32_t*)(uintptr_t)(Bs + gi * 512),
                                       16, 0, 0);
    }
    __syncthreads();
    bf16x8 af[4], bfr[4];
#pragma unroll
    for (int fm = 0; fm < 4; ++fm)
      af[fm] = *(const bf16x8*)(As + (wr * 64 + fm * 16 + lrow) * 32 + lk);
#pragma unroll
    for (int fn = 0; fn < 4; ++fn)
      bfr[fn] = *(const bf16x8*)(Bs + (wc * 64 + fn * 16 + lrow) * 32 + lk);
#pragma unroll
    for (int fm = 0; fm < 4; ++fm)
#pragma unroll
      for (int fn = 0; fn < 4; ++fn)
        acc[fm][fn] = __builtin_amdgcn_mfma_f32_16x16x32_bf16(af[fm], bfr[fn],
                                                              acc[fm][fn], 0, 0, 0);
    __syncthreads();
  }

  float* Cb = C + (size_t)b * N_ * C_ + ((size_t)mt * 128) * C_ + nt * 128;
  const int col = wc * 64 + (l & 15);
  const int rbase = wr * 64 + (l >> 4) * 4;
#pragma unroll
  for (int fm = 0; fm < 4; ++fm)
#pragma unroll
    for (int fn = 0; fn < 4; ++fn)
#pragma unroll
      for (int r = 0; r < 4; ++r)
        Cb[(size_t)(rbase + fm * 16 + r) * C_ + col + fn * 16] = acc[fm][fn][r];
}

// ---------------------------------------------------------------------------
// Workspace layout (bytes), total 78,643,200 (same proven footprint):
//   [0, 33554432)          P frag-partials (f32) -> dead after reduce
//   [0, 62914560)          embaBF (bf16) after reduce
//   [62914560, 66846720)   S (f32) -> then T (f32)
//   [66846720, 74711040)   U, SC (f32) -> then W3bf (bf16)
//   [74711040, 78643200)   PR (f32)
// ---------------------------------------------------------------------------
extern "C" void kernel_launch(void* const* d_in, const int* in_sizes, int n_in,
                              void* d_out, int out_size, void* d_ws, size_t ws_size,
                              hipStream_t stream) {
  const float* emb1 = (const float*)d_in[0];
  const float* emba = (const float*)d_in[1];
  const float* Wq   = (const float*)d_in[2];
  const float* Wk   = (const float*)d_in[3];
  const float* Wv   = (const float*)d_in[4];
  const float* Wo   = (const float*)d_in[5];
  float* out = (float*)d_out;
  char* ws = (char*)d_ws;

  float*  P      = (float*)(ws);
  ushort* embaBF = (ushort*)(ws);
  float*  S      = (float*)(ws + 62914560);
  float*  T      = (float*)(ws + 62914560);
  float*  U      = (float*)(ws + 66846720);
  ushort* W3bf   = (ushort*)(ws + 66846720);
  float*  SCb    = (float*)(ws + 70778880);
  float*  PRb    = (float*)(ws + 74711040);

  // 1) S partials (MFMA, register-pipelined) + reduce/unswizzle
  k1_mfma<<<dim3(32, NSPLIT), 512, 0, stream>>>(emb1, emba, P);
  k_reduce_frag<<<dim3(32, 32), 256, 0, stream>>>((const f32x4*)P, S);

  // 2) emb_all -> bf16 (P region is dead now)
  k_cvt<<<30720, 256, 0, stream>>>((const float4*)emba, (ushort4*)embaBF, 7864320);

  // 3) U = Wq[h] @ S[b,h]                    (M=128, K=128)
  k_small_gemm_t<false><<<dim3(32, 2), 256, 0, stream>>>(
      Wq, 16384, 0, 128, 1,
      S, 30720, 122880, 240, 1,
      U, 30720, 122880, 240, 128, 1.0f);

  // 4) scores = (U @ Wk^T) / sqrt(960)       (M=128, K=240)
  k_small_gemm_t<false><<<dim3(32, 2), 256, 0, stream>>>(
      U, 30720, 122880, 240, 1,
      Wk, 0, 0, 1, 240,
      SCb, 30720, 122880, 240, 240, 0.0322748612183951f);

  // 5) InstanceNorm + softmax -> probs
  k_inorm_softmax<<<32, 256, 0, stream>>>(SCb, PRb);

  // 6) T = probs @ Wv                        (M=128, K=240)
  k_small_gemm_t<false><<<dim3(32, 2), 256, 0, stream>>>(
      PRb, 30720, 122880, 240, 1,
      Wv, 0, 0, 240, 1,
      T, 30720, 122880, 240, 240, 1.0f);

  // 7) W3bf[b,e,h*240+d] = sum_c Wo[e,4c+h] T[c,d]  (M=512, K=128, bf16 out)
  k_small_gemm_t<true><<<dim3(32, 8), 256, 0, stream>>>(
      Wo, 1, 0, 512, 4,
      T, 30720, 122880, 240, 1,
      W3bf, 240, 491520, 960, 128, 1.0f);

  // 8) O1[b] = embaBF[b] @ W3bf[b]^T  (MFMA)
  k3_mfma<<<dim3(32, 4, 8), 256, 0, stream>>>(embaBF, W3bf, out);
}

// Round 5
// 350.957 us; speedup vs baseline: 2.4117x; 1.0102x over previous
//
#include <hip/hip_runtime.h>
#include <cstdint>
#include <cstddef>

#define B_ 8
#define N_ 4096
#define C_ 512
#define KV_ 960
#define DQ 128
#define DK 240
#define NSPLIT 8   // split-K over n for k1; grid 32*8*2 = 512 blocks = 2/CU

typedef __attribute__((ext_vector_type(8))) short bf16x8;
typedef __attribute__((ext_vector_type(4))) float f32x4;
#define AS1 __attribute__((address_space(1)))
#define AS3 __attribute__((address_space(3)))

__device__ __forceinline__ ushort f2bf(float f) {
  uint32_t u = __float_as_uint(f);
  u += 0x7FFFu + ((u >> 16) & 1u);  // RNE
  return (ushort)(u >> 16);
}

__device__ __forceinline__ uint32_t cvtpk(float lo, float hi) {
  uint32_t r;
  asm("v_cvt_pk_bf16_f32 %0, %1, %2" : "=v"(r) : "v"(lo), "v"(hi));
  return r;
}

union bfpack {
  uint32_t u[4];
  ushort s[8];
  bf16x8 v;
};

// ---------------------------------------------------------------------------
// K1 (MFMA, 2 blocks/CU): partial
//   S[b,h,i,j] = sum_{n in split} emb1[b,n,h*128+i] * embaBF[b,n,h*240+j]
// Per block: M=128(i) x N=128(j half; cols >=240 padded) x K=512 n, BK=64.
// A gathered f32 (+cvt_pk), B gathered bf16 (no pack). Register pipeline with
// raw barriers; global loads stay in flight across the MFMA phase.
// grid (32 bh, NSPLIT, 2 jhalf), block 512 (8 waves, 4x2; wave tile 32x64).
// ---------------------------------------------------------------------------
__global__ __launch_bounds__(512) void k1_mfma(const float* __restrict__ emb1,
                                               const ushort* __restrict__ embaBF,
                                               float* __restrict__ P) {
  __shared__ ushort As[128 * 64];  // [i=128][n=64], 16B blocks XOR-swizzled
  __shared__ ushort Bs[128 * 64];  // [j=128][n=64], swizzled
  const int bh = blockIdx.x;
  const int split = blockIdx.y;
  const int jh = blockIdx.z;
  const int b = bh >> 2, h = bh & 3;
  const int t = threadIdx.x;
  const int w = t >> 6, l = t & 63;
  const int wm = w >> 1, wn = w & 1;  // wave tile: rows wm*32, cols wn*64

  const float* Abase = emb1 + (size_t)b * N_ * C_ + h * DQ;    // + n*C_ + c
  const ushort* Bbase = embaBF + (size_t)b * N_ * KV_;         // + n*KV_ + jg

  const int cA = t & 127;   // A gather column (i)
  const int jB = t & 127;   // B gather column (j within half)
  const int nb0 = t >> 7;   // 0..3 base n-block for staging
  int jl = jh * 128 + jB;
  if (jl > DK - 1) jl = DK - 1;  // padded cols duplicate col 239 (discarded)
  const int jg = h * DK + jl;

  f32x4 acc[2][4];
#pragma unroll
  for (int fm = 0; fm < 2; ++fm)
#pragma unroll
    for (int fn = 0; fn < 4; ++fn) acc[fm][fn] = (f32x4){0.f, 0.f, 0.f, 0.f};

  const int n0 = split * (N_ / NSPLIT);
  const int lrow = l & 15;
  const int KS = (N_ / NSPLIT) / 64;  // 8

  float va[2][8];
  ushort ub[2][8];

  // prologue: issue loads for tile 0
#pragma unroll
  for (int q = 0; q < 2; ++q) {
    const float* g = Abase + (size_t)(n0 + (nb0 + q * 4) * 8) * C_ + cA;
#pragma unroll
    for (int kk = 0; kk < 8; ++kk) va[q][kk] = g[(size_t)kk * C_];
  }
#pragma unroll
  for (int q = 0; q < 2; ++q) {
    const ushort* g = Bbase + (size_t)(n0 + (nb0 + q * 4) * 8) * KV_ + jg;
#pragma unroll
    for (int kk = 0; kk < 8; ++kk) ub[q][kk] = g[(size_t)kk * KV_];
  }

  for (int ks = 0; ks < KS; ++ks) {
    // pack/assemble current regs (compiler inserts vmcnt waits here)
    bfpack pa[2], pb[2];
#pragma unroll
    for (int q = 0; q < 2; ++q)
#pragma unroll
      for (int p = 0; p < 4; ++p) pa[q].u[p] = cvtpk(va[q][2 * p], va[q][2 * p + 1]);
#pragma unroll
    for (int q = 0; q < 2; ++q)
#pragma unroll
      for (int kk = 0; kk < 8; ++kk) pb[q].s[kk] = ub[q][kk];

    // barrier 1: previous MFMA phase's ds_reads complete (data-dep lgkm waits)
    __builtin_amdgcn_s_barrier();

    // stage to LDS (swizzled)
#pragma unroll
    for (int q = 0; q < 2; ++q) {
      const int nb = nb0 + q * 4;
      *(bf16x8*)(As + cA * 64 + ((nb ^ (cA & 7)) << 3)) = pa[q].v;
      *(bf16x8*)(Bs + jB * 64 + ((nb ^ (jB & 7)) << 3)) = pb[q].v;
    }

    // issue next tile's global loads; they stay in flight through MFMA phase
    if (ks + 1 < KS) {
      const int nb1 = n0 + (ks + 1) * 64;
#pragma unroll
      for (int q = 0; q < 2; ++q) {
        const float* g = Abase + (size_t)(nb1 + (nb0 + q * 4) * 8) * C_ + cA;
#pragma unroll
        for (int kk = 0; kk < 8; ++kk) va[q][kk] = g[(size_t)kk * C_];
      }
#pragma unroll
      for (int q = 0; q < 2; ++q) {
        const ushort* g = Bbase + (size_t)(nb1 + (nb0 + q * 4) * 8) * KV_ + jg;
#pragma unroll
        for (int kk = 0; kk < 8; ++kk) ub[q][kk] = g[(size_t)kk * KV_];
      }
    }

    // drain DS writes only (global loads keep flying), then barrier 2
    asm volatile("s_waitcnt lgkmcnt(0)" ::: "memory");
    __builtin_amdgcn_sched_barrier(0);
    __builtin_amdgcn_s_barrier();

    // MFMA phase: 2 k-halves x (2x4) fragments
#pragma unroll
    for (int half = 0; half < 2; ++half) {
      const int kb = half * 4 + (l >> 4);  // n-block 0..7
      bf16x8 af[2], bv[4];
#pragma unroll
      for (int fm = 0; fm < 2; ++fm) {
        const int i = wm * 32 + fm * 16 + lrow;
        af[fm] = *(const bf16x8*)(As + i * 64 + ((kb ^ (i & 7)) << 3));
      }
#pragma unroll
      for (int fn = 0; fn < 4; ++fn) {
        const int j = wn * 64 + fn * 16 + lrow;
        bv[fn] = *(const bf16x8*)(Bs + j * 64 + ((kb ^ (j & 7)) << 3));
      }
#pragma unroll
      for (int fm = 0; fm < 2; ++fm)
#pragma unroll
        for (int fn = 0; fn < 4; ++fn)
          acc[fm][fn] = __builtin_amdgcn_mfma_f32_16x16x32_bf16(af[fm], bv[fn],
                                                                acc[fm][fn], 0, 0, 0);
    }
  }
  // fragment-native coalesced store: P[(split,bh,jh)][v=fm*4+fn][t] (f32x4)
  f32x4* Pv4 = (f32x4*)P + ((size_t)(split * 32 + bh) * 2 + jh) * 4096;
#pragma unroll
  for (int fm = 0; fm < 2; ++fm)
#pragma unroll
    for (int fn = 0; fn < 4; ++fn) Pv4[(fm * 4 + fn) * 512 + t] = acc[fm][fn];
}

// ---------------------------------------------------------------------------
// Reduce NSPLIT fragment-native partials and un-swizzle into S[bh][128][240].
// grid (32 bh, 32), block 256.
// ---------------------------------------------------------------------------
__global__ __launch_bounds__(256) void k_reduce_frag(const f32x4* __restrict__ P,
                                                     float* __restrict__ S) {
  const int bh = blockIdx.x;
  const int g = blockIdx.y * 256 + threadIdx.x;  // 0..8191 (jh, v, t)
  const int jh = g >> 12;
  const int rest = g & 4095;
  f32x4 a = P[((size_t)bh * 2 + jh) * 4096 + rest];
#pragma unroll
  for (int s = 1; s < NSPLIT; ++s) {
    f32x4 v = P[((size_t)(s * 32 + bh) * 2 + jh) * 4096 + rest];
    a.x += v.x; a.y += v.y; a.z += v.z; a.w += v.w;
  }
  const int v = rest >> 9, tt = rest & 511;
  const int fm = v >> 2, fn = v & 3;
  const int wv = tt >> 6, l = tt & 63;
  const int wm = wv >> 1, wn = wv & 1;
  const int i0 = wm * 32 + fm * 16 + (l >> 4) * 4;
  const int j = jh * 128 + wn * 64 + fn * 16 + (l & 15);
  if (j < DK) {
    float* sp = S + (size_t)bh * (DQ * DK) + (size_t)i0 * DK + j;
    sp[0] = a.x; sp[DK] = a.y; sp[2 * DK] = a.z; sp[3 * DK] = a.w;
  }
}

// ---------------------------------------------------------------------------
// f32 -> bf16 (RNE), 4 elems/thread
// ---------------------------------------------------------------------------
__global__ __launch_bounds__(256) void k_cvt(const float4* __restrict__ in,
                                             ushort4* __restrict__ out, int n4) {
  int i = blockIdx.x * 256 + threadIdx.x;
  if (i >= n4) return;
  float4 v = in[i];
  ushort4 o;
  o.x = f2bf(v.x); o.y = f2bf(v.y); o.z = f2bf(v.z); o.w = f2bf(v.w);
  out[i] = o;
}

// ---------------------------------------------------------------------------
// Generic small GEMM over the 32 (b,h) problems, N fixed 240.
// ---------------------------------------------------------------------------
template <bool BF16OUT>
__global__ __launch_bounds__(256) void k_small_gemm_t(
    const float* __restrict__ A, int a_h, int a_b, int sa0, int sa1,
    const float* __restrict__ B, int b_h, int b_b, int sb0, int sb1,
    void* __restrict__ Cv, int c_h, int c_b, int ldc, int K, float scale) {
  const int bh = blockIdx.x;
  const int b = bh >> 2, h = bh & 3;
  const int m0 = blockIdx.y * 64;
  const float* Ab = A + (size_t)h * a_h + (size_t)b * a_b;
  const float* Bb = B + (size_t)h * b_h + (size_t)b * b_b;

  __shared__ float Ast[16][64];
  __shared__ float Bst[16][DK];
  const int t = threadIdx.x;
  const int tm = t >> 4, tn = t & 15;
  const int mi = tm * 4, nj = tn * 15;
  float acc[4][15];
#pragma unroll
  for (int x = 0; x < 4; ++x)
#pragma unroll
    for (int y = 0; y < 15; ++y) acc[x][y] = 0.f;

  for (int k0 = 0; k0 < K; k0 += 16) {
    __syncthreads();
#pragma unroll
    for (int q = 0; q < 4; ++q) {
      int idx = t + q * 256;
      int m = idx >> 4, k = idx & 15;
      Ast[k][m] = Ab[(size_t)(m0 + m) * sa0 + (size_t)(k0 + k) * sa1];
    }
#pragma unroll
    for (int q = 0; q < 15; ++q) {
      int idx = t + q * 256;
      int k = idx / DK, n = idx - k * DK;
      Bst[k][n] = Bb[(size_t)(k0 + k) * sb0 + (size_t)n * sb1];
    }
    __syncthreads();
#pragma unroll
    for (int kk = 0; kk < 16; ++kk) {
      float a4[4], bn[15];
#pragma unroll
      for (int x = 0; x < 4; ++x) a4[x] = Ast[kk][mi + x];
#pragma unroll
      for (int y = 0; y < 15; ++y) bn[y] = Bst[kk][nj + y];
#pragma unroll
      for (int x = 0; x < 4; ++x)
#pragma unroll
        for (int y = 0; y < 15; ++y) acc[x][y] = fmaf(a4[x], bn[y], acc[x][y]);
    }
  }
  if (BF16OUT) {
    ushort* Cb = (ushort*)Cv + (size_t)h * c_h + (size_t)b * c_b;
#pragma unroll
    for (int x = 0; x < 4; ++x)
#pragma unroll
      for (int y = 0; y < 15; ++y)
        Cb[(size_t)(m0 + mi + x) * ldc + nj + y] = f2bf(acc[x][y] * scale);
  } else {
    float* Cb = (float*)Cv + (size_t)h * c_h + (size_t)b * c_b;
#pragma unroll
    for (int x = 0; x < 4; ++x)
#pragma unroll
      for (int y = 0; y < 15; ++y)
        Cb[(size_t)(m0 + mi + x) * ldc + nj + y] = acc[x][y] * scale;
  }
}

// ---------------------------------------------------------------------------
// InstanceNorm (biased var, eps 1e-5) + softmax over dk.
// ---------------------------------------------------------------------------
__global__ __launch_bounds__(256) void k_inorm_softmax(const float* __restrict__ SC,
                                                       float* __restrict__ PR) {
  const int bh = blockIdx.x;
  const float* s = SC + (size_t)bh * DQ * DK;
  float* p = PR + (size_t)bh * DQ * DK;
  const int t = threadIdx.x;
  float sum = 0.f, sq = 0.f;
  for (int i = t; i < DQ * DK; i += 256) {
    float v = s[i];
    sum += v;
    sq = fmaf(v, v, sq);
  }
#pragma unroll
  for (int o = 32; o > 0; o >>= 1) {
    sum += __shfl_down(sum, o);
    sq += __shfl_down(sq, o);
  }
  __shared__ float s1[4], s2[4];
  if ((t & 63) == 0) { s1[t >> 6] = sum; s2[t >> 6] = sq; }
  __syncthreads();
  const float ts = s1[0] + s1[1] + s1[2] + s1[3];
  const float tq = s2[0] + s2[1] + s2[2] + s2[3];
  const float mu = ts * (1.f / (DQ * DK));
  const float var = tq * (1.f / (DQ * DK)) - mu * mu;
  const float rstd = rsqrtf(var + 1e-5f);
  if (t < DQ) {
    const float* row = s + t * DK;
    float* prow = p + t * DK;
    float m = -1e30f;
    for (int k = 0; k < DK; ++k) m = fmaxf(m, (row[k] - mu) * rstd);
    float acc = 0.f;
    for (int k = 0; k < DK; ++k) {
      float e = __expf((row[k] - mu) * rstd - m);
      prow[k] = e;
      acc += e;
    }
    const float inv = 1.f / acc;
    for (int k = 0; k < DK; ++k) prow[k] *= inv;
  }
}

// ---------------------------------------------------------------------------
// K3 (MFMA): O1[b,n,e] = sum_g embaBF[b,n,g] * W3bf[b,e,g]
// m97 structure: 128x128 tile, BK=32, 4 waves (2x2), global_load_lds w=16.
// Flat grid 1024 with XCD swizzle: each XCD owns one b (L2 locality),
// mt-major / nt-inner within (A-tile reused 4x consecutively).
// ---------------------------------------------------------------------------
__global__ __launch_bounds__(256) void k3_mfma(const ushort* __restrict__ A,
                                               const ushort* __restrict__ Bw,
                                               float* __restrict__ C) {
  __shared__ ushort As[128 * 32];
  __shared__ ushort Bs[128 * 32];
  const int bid = blockIdx.x;
  const int swz = (bid & 7) * 128 + (bid >> 3);  // bijective, 1024 % 8 == 0
  const int b = swz >> 7;
  const int rem = swz & 127;
  const int mt = rem >> 2, nt = rem & 3;
  const int t = threadIdx.x;
  const int w = t >> 6, l = t & 63;
  const int wr = w >> 1, wc = w & 1;

  const ushort* Ab = A + (size_t)b * N_ * KV_ + (size_t)mt * 128 * KV_;
  const ushort* Bb = Bw + (size_t)b * C_ * KV_ + (size_t)nt * 128 * KV_;

  const int r_l = l >> 2;
  const int c_l = (l & 3) * 8;

  f32x4 acc[4][4];
#pragma unroll
  for (int fm = 0; fm < 4; ++fm)
#pragma unroll
    for (int fn = 0; fn < 4; ++fn) acc[fm][fn] = (f32x4){0.f, 0.f, 0.f, 0.f};

  const int lrow = l & 15;
  const int lk = (l >> 4) * 8;

  for (int k0 = 0; k0 < KV_; k0 += 32) {
#pragma unroll
    for (int inst = 0; inst < 2; ++inst) {
      const int gi = w * 2 + inst;
      const ushort* ga = Ab + (size_t)(gi * 16 + r_l) * KV_ + k0 + c_l;
      __builtin_amdgcn_global_load_lds((AS1 const uint32_t*)(uintptr_t)ga,
                                       (AS3 uint32_t*)(uintptr_t)(As + gi * 512),
                                       16, 0, 0);
      const ushort* gb = Bb + (size_t)(gi * 16 + r_l) * KV_ + k0 + c_l;
      __builtin_amdgcn_global_load_lds((AS1 const uint32_t*)(uintptr_t)gb,
                                       (AS3 uint32_t*)(uintptr_t)(Bs + gi * 512),
                                       16, 0, 0);
    }
    __syncthreads();
    bf16x8 af[4], bfr[4];
#pragma unroll
    for (int fm = 0; fm < 4; ++fm)
      af[fm] = *(const bf16x8*)(As + (wr * 64 + fm * 16 + lrow) * 32 + lk);
#pragma unroll
    for (int fn = 0; fn < 4; ++fn)
      bfr[fn] = *(const bf16x8*)(Bs + (wc * 64 + fn * 16 + lrow) * 32 + lk);
#pragma unroll
    for (int fm = 0; fm < 4; ++fm)
#pragma unroll
      for (int fn = 0; fn < 4; ++fn)
        acc[fm][fn] = __builtin_amdgcn_mfma_f32_16x16x32_bf16(af[fm], bfr[fn],
                                                              acc[fm][fn], 0, 0, 0);
    __syncthreads();
  }

  float* Cb = C + (size_t)b * N_ * C_ + ((size_t)mt * 128) * C_ + nt * 128;
  const int col = wc * 64 + (l & 15);
  const int rbase = wr * 64 + (l >> 4) * 4;
#pragma unroll
  for (int fm = 0; fm < 4; ++fm)
#pragma unroll
    for (int fn = 0; fn < 4; ++fn)
#pragma unroll
      for (int r = 0; r < 4; ++r)
        Cb[(size_t)(rbase + fm * 16 + r) * C_ + col + fn * 16] = acc[fm][fn][r];
}

// ---------------------------------------------------------------------------
// Memory plan (ws 78,643,200 B + d_out as scratch):
//   d_out [0, 33554432)    P frag-partials (f32) -- dead before k3 overwrites
//   ws [0, 62914560)       embaBF (bf16), written by k_cvt FIRST
//   ws [62914560, 66846720) S (f32) -> then T (f32)
//   ws [66846720, 70778880) U (f32)  \ W3bf (bf16, 7.9MB) overlays both
//   ws [70778880, 74711040) SC (f32) /  after U,SC dead
//   ws [74711040, 78643200) PR (f32)
// ---------------------------------------------------------------------------
extern "C" void kernel_launch(void* const* d_in, const int* in_sizes, int n_in,
                              void* d_out, int out_size, void* d_ws, size_t ws_size,
                              hipStream_t stream) {
  const float* emb1 = (const float*)d_in[0];
  const float* emba = (const float*)d_in[1];
  const float* Wq   = (const float*)d_in[2];
  const float* Wk   = (const float*)d_in[3];
  const float* Wv   = (const float*)d_in[4];
  const float* Wo   = (const float*)d_in[5];
  float* out = (float*)d_out;
  char* ws = (char*)d_ws;

  ushort* embaBF = (ushort*)(ws);
  float*  S      = (float*)(ws + 62914560);
  float*  T      = (float*)(ws + 62914560);
  float*  U      = (float*)(ws + 66846720);
  ushort* W3bf   = (ushort*)(ws + 66846720);
  float*  SCb    = (float*)(ws + 70778880);
  float*  PRb    = (float*)(ws + 74711040);
  float*  P      = out;  // split-K partials live in d_out until k3 overwrites

  // 1) emb_all -> bf16 (feeds both k1's B-gather and k3's A)
  k_cvt<<<30720, 256, 0, stream>>>((const float4*)emba, (ushort4*)embaBF, 7864320);

  // 2) S partials (MFMA, 2 blocks/CU) + reduce/unswizzle
  k1_mfma<<<dim3(32, NSPLIT, 2), 512, 0, stream>>>(emb1, embaBF, P);
  k_reduce_frag<<<dim3(32, 32), 256, 0, stream>>>((const f32x4*)P, S);

  // 3) U = Wq[h] @ S[b,h]                    (M=128, K=128)
  k_small_gemm_t<false><<<dim3(32, 2), 256, 0, stream>>>(
      Wq, 16384, 0, 128, 1,
      S, 30720, 122880, 240, 1,
      U, 30720, 122880, 240, 128, 1.0f);

  // 4) scores = (U @ Wk^T) / sqrt(960)       (M=128, K=240)
  k_small_gemm_t<false><<<dim3(32, 2), 256, 0, stream>>>(
      U, 30720, 122880, 240, 1,
      Wk, 0, 0, 1, 240,
      SCb, 30720, 122880, 240, 240, 0.0322748612183951f);

  // 5) InstanceNorm + softmax -> probs
  k_inorm_softmax<<<32, 256, 0, stream>>>(SCb, PRb);

  // 6) T = probs @ Wv                        (M=128, K=240)  [S slot dead]
  k_small_gemm_t<false><<<dim3(32, 2), 256, 0, stream>>>(
      PRb, 30720, 122880, 240, 1,
      Wv, 0, 0, 240, 1,
      T, 30720, 122880, 240, 240, 1.0f);

  // 7) W3bf[b,e,h*240+d] = sum_c Wo[e,4c+h] T[c,d]  (M=512, K=128, bf16 out)
  k_small_gemm_t<true><<<dim3(32, 8), 256, 0, stream>>>(
      Wo, 1, 0, 512, 4,
      T, 30720, 122880, 240, 1,
      W3bf, 240, 491520, 960, 128, 1.0f);

  // 8) O1[b] = embaBF[b] @ W3bf[b]^T  (MFMA, XCD-swizzled flat grid)
  k3_mfma<<<1024, 256, 0, stream>>>(embaBF, W3bf, out);
}

// Round 6
// 243.560 us; speedup vs baseline: 3.4752x; 1.4409x over previous
//
#include <hip/hip_runtime.h>
#include <cstdint>
#include <cstddef>

#define B_ 8
#define N_ 4096
#define C_ 512
#define KV_ 960
#define DQ 128
#define DK 240
#define NSPLIT 8   // split-K over n for k1; grid 32*8*2 = 512 blocks = 2/CU

typedef __attribute__((ext_vector_type(8))) short bf16x8;
typedef __attribute__((ext_vector_type(4))) float f32x4;
#define AS1 __attribute__((address_space(1)))
#define AS3 __attribute__((address_space(3)))

__device__ __forceinline__ ushort f2bf(float f) {
  uint32_t u = __float_as_uint(f);
  u += 0x7FFFu + ((u >> 16) & 1u);  // RNE
  return (ushort)(u >> 16);
}

__device__ __forceinline__ uint32_t cvtpk(float lo, float hi) {
  uint32_t r;
  asm("v_cvt_pk_bf16_f32 %0, %1, %2" : "=v"(r) : "v"(lo), "v"(hi));
  return r;
}

union bfpack {
  uint32_t u[4];
  ushort s[8];
  bf16x8 v;
};

// ---------------------------------------------------------------------------
// K1 (MFMA, 2 blocks/CU): partial S — unchanged from R4/R5.
// ---------------------------------------------------------------------------
__global__ __launch_bounds__(512) void k1_mfma(const float* __restrict__ emb1,
                                               const ushort* __restrict__ embaBF,
                                               float* __restrict__ P) {
  __shared__ ushort As[128 * 64];
  __shared__ ushort Bs[128 * 64];
  const int bh = blockIdx.x;
  const int split = blockIdx.y;
  const int jh = blockIdx.z;
  const int b = bh >> 2, h = bh & 3;
  const int t = threadIdx.x;
  const int w = t >> 6, l = t & 63;
  const int wm = w >> 1, wn = w & 1;

  const float* Abase = emb1 + (size_t)b * N_ * C_ + h * DQ;
  const ushort* Bbase = embaBF + (size_t)b * N_ * KV_;

  const int cA = t & 127;
  const int jB = t & 127;
  const int nb0 = t >> 7;
  int jl = jh * 128 + jB;
  if (jl > DK - 1) jl = DK - 1;
  const int jg = h * DK + jl;

  f32x4 acc[2][4];
#pragma unroll
  for (int fm = 0; fm < 2; ++fm)
#pragma unroll
    for (int fn = 0; fn < 4; ++fn) acc[fm][fn] = (f32x4){0.f, 0.f, 0.f, 0.f};

  const int n0 = split * (N_ / NSPLIT);
  const int lrow = l & 15;
  const int KS = (N_ / NSPLIT) / 64;

  float va[2][8];
  ushort ub[2][8];

#pragma unroll
  for (int q = 0; q < 2; ++q) {
    const float* g = Abase + (size_t)(n0 + (nb0 + q * 4) * 8) * C_ + cA;
#pragma unroll
    for (int kk = 0; kk < 8; ++kk) va[q][kk] = g[(size_t)kk * C_];
  }
#pragma unroll
  for (int q = 0; q < 2; ++q) {
    const ushort* g = Bbase + (size_t)(n0 + (nb0 + q * 4) * 8) * KV_ + jg;
#pragma unroll
    for (int kk = 0; kk < 8; ++kk) ub[q][kk] = g[(size_t)kk * KV_];
  }

  for (int ks = 0; ks < KS; ++ks) {
    bfpack pa[2], pb[2];
#pragma unroll
    for (int q = 0; q < 2; ++q)
#pragma unroll
      for (int p = 0; p < 4; ++p) pa[q].u[p] = cvtpk(va[q][2 * p], va[q][2 * p + 1]);
#pragma unroll
    for (int q = 0; q < 2; ++q)
#pragma unroll
      for (int kk = 0; kk < 8; ++kk) pb[q].s[kk] = ub[q][kk];

    __builtin_amdgcn_s_barrier();

#pragma unroll
    for (int q = 0; q < 2; ++q) {
      const int nb = nb0 + q * 4;
      *(bf16x8*)(As + cA * 64 + ((nb ^ (cA & 7)) << 3)) = pa[q].v;
      *(bf16x8*)(Bs + jB * 64 + ((nb ^ (jB & 7)) << 3)) = pb[q].v;
    }

    if (ks + 1 < KS) {
      const int nb1 = n0 + (ks + 1) * 64;
#pragma unroll
      for (int q = 0; q < 2; ++q) {
        const float* g = Abase + (size_t)(nb1 + (nb0 + q * 4) * 8) * C_ + cA;
#pragma unroll
        for (int kk = 0; kk < 8; ++kk) va[q][kk] = g[(size_t)kk * C_];
      }
#pragma unroll
      for (int q = 0; q < 2; ++q) {
        const ushort* g = Bbase + (size_t)(nb1 + (nb0 + q * 4) * 8) * KV_ + jg;
#pragma unroll
        for (int kk = 0; kk < 8; ++kk) ub[q][kk] = g[(size_t)kk * KV_];
      }
    }

    asm volatile("s_waitcnt lgkmcnt(0)" ::: "memory");
    __builtin_amdgcn_sched_barrier(0);
    __builtin_amdgcn_s_barrier();

#pragma unroll
    for (int half = 0; half < 2; ++half) {
      const int kb = half * 4 + (l >> 4);
      bf16x8 af[2], bv[4];
#pragma unroll
      for (int fm = 0; fm < 2; ++fm) {
        const int i = wm * 32 + fm * 16 + lrow;
        af[fm] = *(const bf16x8*)(As + i * 64 + ((kb ^ (i & 7)) << 3));
      }
#pragma unroll
      for (int fn = 0; fn < 4; ++fn) {
        const int j = wn * 64 + fn * 16 + lrow;
        bv[fn] = *(const bf16x8*)(Bs + j * 64 + ((kb ^ (j & 7)) << 3));
      }
#pragma unroll
      for (int fm = 0; fm < 2; ++fm)
#pragma unroll
        for (int fn = 0; fn < 4; ++fn)
          acc[fm][fn] = __builtin_amdgcn_mfma_f32_16x16x32_bf16(af[fm], bv[fn],
                                                                acc[fm][fn], 0, 0, 0);
    }
  }
  f32x4* Pv4 = (f32x4*)P + ((size_t)(split * 32 + bh) * 2 + jh) * 4096;
#pragma unroll
  for (int fm = 0; fm < 2; ++fm)
#pragma unroll
    for (int fn = 0; fn < 4; ++fn) Pv4[(fm * 4 + fn) * 512 + t] = acc[fm][fn];
}

// ---------------------------------------------------------------------------
// Reduce NSPLIT fragment-native partials and un-swizzle into S[bh][128][240].
// ---------------------------------------------------------------------------
__global__ __launch_bounds__(256) void k_reduce_frag(const f32x4* __restrict__ P,
                                                     float* __restrict__ S) {
  const int bh = blockIdx.x;
  const int g = blockIdx.y * 256 + threadIdx.x;
  const int jh = g >> 12;
  const int rest = g & 4095;
  f32x4 a = P[((size_t)bh * 2 + jh) * 4096 + rest];
#pragma unroll
  for (int s = 1; s < NSPLIT; ++s) {
    f32x4 v = P[((size_t)(s * 32 + bh) * 2 + jh) * 4096 + rest];
    a.x += v.x; a.y += v.y; a.z += v.z; a.w += v.w;
  }
  const int v = rest >> 9, tt = rest & 511;
  const int fm = v >> 2, fn = v & 3;
  const int wv = tt >> 6, l = tt & 63;
  const int wm = wv >> 1, wn = wv & 1;
  const int i0 = wm * 32 + fm * 16 + (l >> 4) * 4;
  const int j = jh * 128 + wn * 64 + fn * 16 + (l & 15);
  if (j < DK) {
    float* sp = S + (size_t)bh * (DQ * DK) + (size_t)i0 * DK + j;
    sp[0] = a.x; sp[DK] = a.y; sp[2 * DK] = a.z; sp[3 * DK] = a.w;
  }
}

// ---------------------------------------------------------------------------
// f32 -> bf16 (RNE), 4 elems/thread
// ---------------------------------------------------------------------------
__global__ __launch_bounds__(256) void k_cvt(const float4* __restrict__ in,
                                             ushort4* __restrict__ out, int n4) {
  int i = blockIdx.x * 256 + threadIdx.x;
  if (i >= n4) return;
  float4 v = in[i];
  ushort4 o;
  o.x = f2bf(v.x); o.y = f2bf(v.y); o.z = f2bf(v.z); o.w = f2bf(v.w);
  out[i] = o;
}

// ===========================================================================
// Flat-batched f32 chain GEMMs. Block tile 64m x 48n, thread tile 4x3,
// 256 threads, padded LDS (conflict-free). K multiple of 16.
// ===========================================================================

// g1: U[(b4+h)][c][j] = sum_d Wq[h][c][d] * S[(b4+h)][d][j]
// grid (4 h, 2 mt, 40 z=b*5+nt)
__global__ __launch_bounds__(256) void k_g1(const float* __restrict__ Wq,
                                            const float* __restrict__ S,
                                            float* __restrict__ U) {
  const int h = blockIdx.x, c0 = blockIdx.y * 64;
  const int b = blockIdx.z / 5, n0 = (blockIdx.z % 5) * 48;
  const float* A = Wq + (size_t)h * 16384;
  const float* Bp = S + (size_t)(b * 4 + h) * 30720 + n0;
  float* Cp = U + (size_t)(b * 4 + h) * 30720 + n0;
  __shared__ float Ast[16][65];
  __shared__ float Bst[16][49];
  const int t = threadIdx.x;
  const int mi = (t >> 4) * 4, nj = (t & 15) * 3;
  float acc[4][3] = {};
  for (int k0 = 0; k0 < 128; k0 += 16) {
    __syncthreads();
#pragma unroll
    for (int q = 0; q < 4; ++q) {
      int idx = t + q * 256, m = idx >> 4, k = idx & 15;
      Ast[k][m] = A[(size_t)(c0 + m) * 128 + k0 + k];
    }
#pragma unroll
    for (int q = 0; q < 3; ++q) {
      int idx = t + q * 256, k = idx / 48, n = idx % 48;
      Bst[k][n] = Bp[(size_t)(k0 + k) * 240 + n];
    }
    __syncthreads();
#pragma unroll
    for (int kk = 0; kk < 16; ++kk) {
      float a4[4], b3[3];
#pragma unroll
      for (int x = 0; x < 4; ++x) a4[x] = Ast[kk][mi + x];
#pragma unroll
      for (int y = 0; y < 3; ++y) b3[y] = Bst[kk][nj + y];
#pragma unroll
      for (int x = 0; x < 4; ++x)
#pragma unroll
        for (int y = 0; y < 3; ++y) acc[x][y] = fmaf(a4[x], b3[y], acc[x][y]);
    }
  }
#pragma unroll
  for (int x = 0; x < 4; ++x)
#pragma unroll
    for (int y = 0; y < 3; ++y)
      Cp[(size_t)(c0 + mi + x) * 240 + nj + y] = acc[x][y];
}

// g2: SC[r][k] = scale * sum_d U[r][d] * Wk[k][d]   (r flat 0..4095)
// grid (64 mt, 5 nt). B staged transposed: Bst2[n][kd].
__global__ __launch_bounds__(256) void k_g2(const float* __restrict__ U,
                                            const float* __restrict__ Wk,
                                            float* __restrict__ SC) {
  const int m0 = blockIdx.x * 64, n0 = blockIdx.y * 48;
  __shared__ float Ast[16][65];
  __shared__ float Bst2[48][17];
  const int t = threadIdx.x;
  const int mi = (t >> 4) * 4, nj = (t & 15) * 3;
  float acc[4][3] = {};
  for (int k0 = 0; k0 < 240; k0 += 16) {
    __syncthreads();
#pragma unroll
    for (int q = 0; q < 4; ++q) {
      int idx = t + q * 256, m = idx >> 4, k = idx & 15;
      Ast[k][m] = U[(size_t)(m0 + m) * 240 + k0 + k];
    }
#pragma unroll
    for (int q = 0; q < 3; ++q) {
      int idx = t + q * 256, n = idx >> 4, kd = idx & 15;
      Bst2[n][kd] = Wk[(size_t)(n0 + n) * 240 + k0 + kd];
    }
    __syncthreads();
#pragma unroll
    for (int kk = 0; kk < 16; ++kk) {
      float a4[4], b3[3];
#pragma unroll
      for (int x = 0; x < 4; ++x) a4[x] = Ast[kk][mi + x];
#pragma unroll
      for (int y = 0; y < 3; ++y) b3[y] = Bst2[nj + y][kk];
#pragma unroll
      for (int x = 0; x < 4; ++x)
#pragma unroll
        for (int y = 0; y < 3; ++y) acc[x][y] = fmaf(a4[x], b3[y], acc[x][y]);
    }
  }
  const float scale = 0.0322748612183951f;
#pragma unroll
  for (int x = 0; x < 4; ++x)
#pragma unroll
    for (int y = 0; y < 3; ++y)
      SC[(size_t)(m0 + mi + x) * 240 + n0 + nj + y] = acc[x][y] * scale;
}

// g3: T[r][d] = sum_k PR[r][k] * Wv[k][d]   (r flat 0..4095)
// grid (64 mt, 5 nt).
__global__ __launch_bounds__(256) void k_g3(const float* __restrict__ PR,
                                            const float* __restrict__ Wv,
                                            float* __restrict__ T) {
  const int m0 = blockIdx.x * 64, n0 = blockIdx.y * 48;
  __shared__ float Ast[16][65];
  __shared__ float Bst[16][49];
  const int t = threadIdx.x;
  const int mi = (t >> 4) * 4, nj = (t & 15) * 3;
  float acc[4][3] = {};
  for (int k0 = 0; k0 < 240; k0 += 16) {
    __syncthreads();
#pragma unroll
    for (int q = 0; q < 4; ++q) {
      int idx = t + q * 256, m = idx >> 4, k = idx & 15;
      Ast[k][m] = PR[(size_t)(m0 + m) * 240 + k0 + k];
    }
#pragma unroll
    for (int q = 0; q < 3; ++q) {
      int idx = t + q * 256, k = idx / 48, n = idx % 48;
      Bst[k][n] = Wv[(size_t)(k0 + k) * 240 + n0 + n];
    }
    __syncthreads();
#pragma unroll
    for (int kk = 0; kk < 16; ++kk) {
      float a4[4], b3[3];
#pragma unroll
      for (int x = 0; x < 4; ++x) a4[x] = Ast[kk][mi + x];
#pragma unroll
      for (int y = 0; y < 3; ++y) b3[y] = Bst[kk][nj + y];
#pragma unroll
      for (int x = 0; x < 4; ++x)
#pragma unroll
        for (int y = 0; y < 3; ++y) acc[x][y] = fmaf(a4[x], b3[y], acc[x][y]);
    }
  }
#pragma unroll
  for (int x = 0; x < 4; ++x)
#pragma unroll
    for (int y = 0; y < 3; ++y)
      T[(size_t)(m0 + mi + x) * 240 + n0 + nj + y] = acc[x][y];
}

// g4: W3bf[b][e][h*240+d] = f2bf( sum_c Wo[e][4c+h] * T[(b4+h)][c][d] )
// grid (4 h, 8 mt, 40 z=b*5+nt). K=128.
__global__ __launch_bounds__(256) void k_g4(const float* __restrict__ Wo,
                                            const float* __restrict__ T,
                                            ushort* __restrict__ W3bf) {
  const int h = blockIdx.x, e0 = blockIdx.y * 64;
  const int b = blockIdx.z / 5, n0 = (blockIdx.z % 5) * 48;
  const float* Bp = T + (size_t)(b * 4 + h) * 30720 + n0;
  ushort* Cp = W3bf + (size_t)b * 491520 + h * 240 + n0;
  __shared__ float Ast[16][65];
  __shared__ float Bst[16][49];
  const int t = threadIdx.x;
  const int mi = (t >> 4) * 4, nj = (t & 15) * 3;
  float acc[4][3] = {};
  for (int k0 = 0; k0 < 128; k0 += 16) {
    __syncthreads();
#pragma unroll
    for (int q = 0; q < 4; ++q) {
      int idx = t + q * 256, m = idx >> 4, k = idx & 15;
      Ast[k][m] = Wo[(size_t)(e0 + m) * 512 + 4 * (k0 + k) + h];
    }
#pragma unroll
    for (int q = 0; q < 3; ++q) {
      int idx = t + q * 256, k = idx / 48, n = idx % 48;
      Bst[k][n] = Bp[(size_t)(k0 + k) * 240 + n];
    }
    __syncthreads();
#pragma unroll
    for (int kk = 0; kk < 16; ++kk) {
      float a4[4], b3[3];
#pragma unroll
      for (int x = 0; x < 4; ++x) a4[x] = Ast[kk][mi + x];
#pragma unroll
      for (int y = 0; y < 3; ++y) b3[y] = Bst[kk][nj + y];
#pragma unroll
      for (int x = 0; x < 4; ++x)
#pragma unroll
        for (int y = 0; y < 3; ++y) acc[x][y] = fmaf(a4[x], b3[y], acc[x][y]);
    }
  }
#pragma unroll
  for (int x = 0; x < 4; ++x)
#pragma unroll
    for (int y = 0; y < 3; ++y)
      Cp[(size_t)(e0 + mi + x) * 960 + nj + y] = f2bf(acc[x][y]);
}

// ---------------------------------------------------------------------------
// Stats: mu, rstd per (b,h) score map (biased var, eps 1e-5). grid 32, blk 1024
// ---------------------------------------------------------------------------
__global__ __launch_bounds__(1024) void k_stats(const float* __restrict__ SC,
                                                float* __restrict__ stats) {
  const int bh = blockIdx.x;
  const float* s = SC + (size_t)bh * 30720;
  const int t = threadIdx.x;
  float sum = 0.f, sq = 0.f;
  for (int i = t; i < 30720; i += 1024) {
    float v = s[i];
    sum += v;
    sq = fmaf(v, v, sq);
  }
#pragma unroll
  for (int o = 32; o > 0; o >>= 1) {
    sum += __shfl_down(sum, o);
    sq += __shfl_down(sq, o);
  }
  __shared__ float s1[16], s2[16];
  if ((t & 63) == 0) { s1[t >> 6] = sum; s2[t >> 6] = sq; }
  __syncthreads();
  if (t == 0) {
    float ts = 0.f, tq = 0.f;
#pragma unroll
    for (int i = 0; i < 16; ++i) { ts += s1[i]; tq += s2[i]; }
    const float mu = ts * (1.f / 30720.f);
    const float var = tq * (1.f / 30720.f) - mu * mu;
    stats[bh * 2] = mu;
    stats[bh * 2 + 1] = rsqrtf(var + 1e-5f);
  }
}

// ---------------------------------------------------------------------------
// Softmax over dk rows of normed scores. grid (32 bh, 4), block 512 (8 waves);
// each wave owns 4 rows; 240 cols -> 4 vals/lane (lane>=48 pads last).
// ---------------------------------------------------------------------------
__global__ __launch_bounds__(512) void k_softmax(const float* __restrict__ SC,
                                                 const float* __restrict__ stats,
                                                 float* __restrict__ PR) {
  const int bh = blockIdx.x;
  const float mu = stats[bh * 2], rstd = stats[bh * 2 + 1];
  const int wv = threadIdx.x >> 6, l = threadIdx.x & 63;
  const int row0 = blockIdx.y * 32 + wv * 4;
  const float* s = SC + (size_t)bh * 30720;
  float* p = PR + (size_t)bh * 30720;
#pragma unroll
  for (int r = 0; r < 4; ++r) {
    const float* srow = s + (size_t)(row0 + r) * 240;
    float* prow = p + (size_t)(row0 + r) * 240;
    float x0 = (srow[l] - mu) * rstd;
    float x1 = (srow[64 + l] - mu) * rstd;
    float x2 = (srow[128 + l] - mu) * rstd;
    float x3 = (l < 48) ? (srow[192 + l] - mu) * rstd : -1e30f;
    float m = fmaxf(fmaxf(x0, x1), fmaxf(x2, x3));
#pragma unroll
    for (int o = 32; o > 0; o >>= 1) m = fmaxf(m, __shfl_xor(m, o));
    float e0 = __expf(x0 - m), e1 = __expf(x1 - m), e2 = __expf(x2 - m);
    float e3 = (l < 48) ? __expf(x3 - m) : 0.f;
    float ss = e0 + e1 + e2 + e3;
#pragma unroll
    for (int o = 32; o > 0; o >>= 1) ss += __shfl_xor(ss, o);
    const float inv = 1.f / ss;
    prow[l] = e0 * inv;
    prow[64 + l] = e1 * inv;
    prow[128 + l] = e2 * inv;
    if (l < 48) prow[192 + l] = e3 * inv;
  }
}

// ---------------------------------------------------------------------------
// K3 (MFMA): unchanged (128x128 tile, XCD-swizzled flat grid).
// ---------------------------------------------------------------------------
__global__ __launch_bounds__(256) void k3_mfma(const ushort* __restrict__ A,
                                               const ushort* __restrict__ Bw,
                                               float* __restrict__ C) {
  __shared__ ushort As[128 * 32];
  __shared__ ushort Bs[128 * 32];
  const int bid = blockIdx.x;
  const int swz = (bid & 7) * 128 + (bid >> 3);
  const int b = swz >> 7;
  const int rem = swz & 127;
  const int mt = rem >> 2, nt = rem & 3;
  const int t = threadIdx.x;
  const int w = t >> 6, l = t & 63;
  const int wr = w >> 1, wc = w & 1;

  const ushort* Ab = A + (size_t)b * N_ * KV_ + (size_t)mt * 128 * KV_;
  const ushort* Bb = Bw + (size_t)b * C_ * KV_ + (size_t)nt * 128 * KV_;

  const int r_l = l >> 2;
  const int c_l = (l & 3) * 8;

  f32x4 acc[4][4];
#pragma unroll
  for (int fm = 0; fm < 4; ++fm)
#pragma unroll
    for (int fn = 0; fn < 4; ++fn) acc[fm][fn] = (f32x4){0.f, 0.f, 0.f, 0.f};

  const int lrow = l & 15;
  const int lk = (l >> 4) * 8;

  for (int k0 = 0; k0 < KV_; k0 += 32) {
#pragma unroll
    for (int inst = 0; inst < 2; ++inst) {
      const int gi = w * 2 + inst;
      const ushort* ga = Ab + (size_t)(gi * 16 + r_l) * KV_ + k0 + c_l;
      __builtin_amdgcn_global_load_lds((AS1 const uint32_t*)(uintptr_t)ga,
                                       (AS3 uint32_t*)(uintptr_t)(As + gi * 512),
                                       16, 0, 0);
      const ushort* gb = Bb + (size_t)(gi * 16 + r_l) * KV_ + k0 + c_l;
      __builtin_amdgcn_global_load_lds((AS1 const uint32_t*)(uintptr_t)gb,
                                       (AS3 uint32_t*)(uintptr_t)(Bs + gi * 512),
                                       16, 0, 0);
    }
    __syncthreads();
    bf16x8 af[4], bfr[4];
#pragma unroll
    for (int fm = 0; fm < 4; ++fm)
      af[fm] = *(const bf16x8*)(As + (wr * 64 + fm * 16 + lrow) * 32 + lk);
#pragma unroll
    for (int fn = 0; fn < 4; ++fn)
      bfr[fn] = *(const bf16x8*)(Bs + (wc * 64 + fn * 16 + lrow) * 32 + lk);
#pragma unroll
    for (int fm = 0; fm < 4; ++fm)
#pragma unroll
      for (int fn = 0; fn < 4; ++fn)
        acc[fm][fn] = __builtin_amdgcn_mfma_f32_16x16x32_bf16(af[fm], bfr[fn],
                                                              acc[fm][fn], 0, 0, 0);
    __syncthreads();
  }

  float* Cb = C + (size_t)b * N_ * C_ + ((size_t)mt * 128) * C_ + nt * 128;
  const int col = wc * 64 + (l & 15);
  const int rbase = wr * 64 + (l >> 4) * 4;
#pragma unroll
  for (int fm = 0; fm < 4; ++fm)
#pragma unroll
    for (int fn = 0; fn < 4; ++fn)
#pragma unroll
      for (int r = 0; r < 4; ++r)
        Cb[(size_t)(rbase + fm * 16 + r) * C_ + col + fn * 16] = acc[fm][fn][r];
}

// ---------------------------------------------------------------------------
// Memory plan (ws 78,643,200 B + d_out as scratch):
//   d_out [0, 33554432)     P frag-partials -- dead before k3 overwrites
//   d_out [41943040, +256)  stats (mu,rstd per bh) -- dead before k3
//   ws [0, 62914560)        embaBF (bf16), written FIRST
//   ws [62914560, 66846720) S (f32) -> then T (f32, after g1)
//   ws [66846720, 70778880) U (f32)  \ W3bf (bf16) overlays after U,SC dead
//   ws [70778880, 74711040) SC (f32) /
//   ws [74711040, 78643200) PR (f32)
// ---------------------------------------------------------------------------
extern "C" void kernel_launch(void* const* d_in, const int* in_sizes, int n_in,
                              void* d_out, int out_size, void* d_ws, size_t ws_size,
                              hipStream_t stream) {
  const float* emb1 = (const float*)d_in[0];
  const float* emba = (const float*)d_in[1];
  const float* Wq   = (const float*)d_in[2];
  const float* Wk   = (const float*)d_in[3];
  const float* Wv   = (const float*)d_in[4];
  const float* Wo   = (const float*)d_in[5];
  float* out = (float*)d_out;
  char* ws = (char*)d_ws;

  ushort* embaBF = (ushort*)(ws);
  float*  S      = (float*)(ws + 62914560);
  float*  T      = (float*)(ws + 62914560);
  float*  U      = (float*)(ws + 66846720);
  ushort* W3bf   = (ushort*)(ws + 66846720);
  float*  SCb    = (float*)(ws + 70778880);
  float*  PRb    = (float*)(ws + 74711040);
  float*  P      = out;
  float*  stats  = (float*)((char*)d_out + 41943040);

  // 1) emb_all -> bf16
  k_cvt<<<30720, 256, 0, stream>>>((const float4*)emba, (ushort4*)embaBF, 7864320);

  // 2) S partials (MFMA) + reduce/unswizzle
  k1_mfma<<<dim3(32, NSPLIT, 2), 512, 0, stream>>>(emb1, embaBF, P);
  k_reduce_frag<<<dim3(32, 32), 256, 0, stream>>>((const f32x4*)P, S);

  // 3) chain (flat-batched f32 GEMMs + stats + softmax)
  k_g1<<<dim3(4, 2, 40), 256, 0, stream>>>(Wq, S, U);
  k_g2<<<dim3(64, 5), 256, 0, stream>>>(U, Wk, SCb);
  k_stats<<<32, 1024, 0, stream>>>(SCb, stats);
  k_softmax<<<dim3(32, 4), 512, 0, stream>>>(SCb, stats, PRb);
  k_g3<<<dim3(64, 5), 256, 0, stream>>>(PRb, Wv, T);
  k_g4<<<dim3(4, 8, 40), 256, 0, stream>>>(Wo, T, W3bf);

  // 4) O1[b] = embaBF[b] @ W3bf[b]^T  (MFMA, XCD-swizzled)
  k3_mfma<<<1024, 256, 0, stream>>>(embaBF, W3bf, out);
}